// Round 1
// baseline (1078.054 us; speedup 1.0000x reference)
//
#include <hip/hip_runtime.h>
#include <hip/hip_bf16.h>

using short8 = __attribute__((ext_vector_type(8))) short;
using f32x4  = __attribute__((ext_vector_type(4))) float;

#define DEVI __device__ __forceinline__

// bf16 <-> f32 via bit math (RNE), no API dependency
DEVI unsigned short f2bf(float f){
  unsigned int u = __float_as_uint(f);
  unsigned int r = (u + 0x7fffu + ((u >> 16) & 1u)) >> 16;
  return (unsigned short)r;
}
DEVI float bf2f(unsigned short u){ return __uint_as_float(((unsigned int)u) << 16); }

DEVI float wsum(float x){
  #pragma unroll
  for (int o = 32; o > 0; o >>= 1) x += __shfl_xor(x, o, 64);
  return x;
}
DEVI float wmax(float x){
  #pragma unroll
  for (int o = 32; o > 0; o >>= 1) x = fmaxf(x, __shfl_xor(x, o, 64));
  return x;
}

DEVI void async16(const void* g, void* l){
  __builtin_amdgcn_global_load_lds(
      (const __attribute__((address_space(1))) void*)g,
      (__attribute__((address_space(3))) void*)l,
      16, 0, 0);
}

// ---------------------------------------------------------------- weight casts
__global__ void tobf16_kernel(const float* __restrict__ in, unsigned short* __restrict__ out, int n){
  int i = blockIdx.x * 256 + threadIdx.x;
  if (i < n) out[i] = f2bf(in[i]);
}

// pool_v_w (dv, c, 4, 4) f32 -> wvb[dv][ij*64 + c] bf16  (k = ij*64 + c)
__global__ void conv_wv_kernel(const float* __restrict__ wv, unsigned short* __restrict__ wvb){
  int i = blockIdx.x * 256 + threadIdx.x;   // 64*64*16 = 65536
  if (i >= 65536) return;
  int dv = i >> 10, c = (i >> 4) & 63, ij = i & 15;
  wvb[dv * 1024 + ij * 64 + c] = f2bf(wv[i]);
}

// ---------------------------------------------------------------- LN over 768, f32 in -> bf16 out
__global__ __launch_bounds__(256)
void ln768_kernel(const float* __restrict__ x, const float* __restrict__ w,
                  const float* __restrict__ b, unsigned short* __restrict__ out)
{
  const int row  = blockIdx.x * 4 + (threadIdx.x >> 6);
  const int lane = threadIdx.x & 63;
  const float* xr = x + (size_t)row * 768;
  f32x4 v[3];
  float s = 0.f, s2 = 0.f;
  #pragma unroll
  for (int kk = 0; kk < 3; kk++){
    v[kk] = *(const f32x4*)&xr[lane * 4 + kk * 256];
    #pragma unroll
    for (int e = 0; e < 4; e++){ s += v[kk][e]; s2 += v[kk][e] * v[kk][e]; }
  }
  s = wsum(s); s2 = wsum(s2);
  float mu  = s * (1.f / 768.f);
  float var = s2 * (1.f / 768.f) - mu * mu;
  float rs  = rsqrtf(var + 1e-6f);
  unsigned short* orow = out + (size_t)row * 768;
  #pragma unroll
  for (int kk = 0; kk < 3; kk++){
    int c0 = lane * 4 + kk * 256;
    float y0 = (v[kk][0] - mu) * rs * w[c0 + 0] + b[c0 + 0];
    float y1 = (v[kk][1] - mu) * rs * w[c0 + 1] + b[c0 + 1];
    float y2 = (v[kk][2] - mu) * rs * w[c0 + 2] + b[c0 + 2];
    float y3 = (v[kk][3] - mu) * rs * w[c0 + 3] + b[c0 + 3];
    unsigned int lo = (unsigned int)f2bf(y0) | ((unsigned int)f2bf(y1) << 16);
    unsigned int hi = (unsigned int)f2bf(y2) | ((unsigned int)f2bf(y3) << 16);
    *(uint2*)&orow[c0] = make_uint2(lo, hi);
  }
}

// ---------------------------------------------------------------- LN over contiguous 64-chunks, in-place
__global__ __launch_bounds__(256)
void ln64_kernel(float* __restrict__ buf, const float* __restrict__ w,
                 const float* __restrict__ b, float eps)
{
  const size_t chunk = (size_t)blockIdx.x * 4 + (threadIdx.x >> 6);
  const int lane = threadIdx.x & 63;
  float xv = buf[chunk * 64 + lane];
  float mu = wsum(xv) * (1.f / 64.f);
  float dl = xv - mu;
  float var = wsum(dl * dl) * (1.f / 64.f);
  buf[chunk * 64 + lane] = dl * rsqrtf(var + eps) * w[lane] + b[lane];
}

// ---------------------------------------------------------------- 128x128 MFMA bf16 B^T GEMM
// C[m][n] = sum_k A[m][k] * W[n][k] + bias[n];  M%128==0, N%128==0, K%32==0
template <int OUT_BF16>
__global__ __launch_bounds__(256, 2)
void gemm_bt(const unsigned short* __restrict__ A, const unsigned short* __restrict__ W,
             const float* __restrict__ bias, void* __restrict__ Cout,
             int M, int N, int K)
{
  __shared__ short8 As8[512];   // 128 rows x 32 bf16
  __shared__ short8 Bs8[512];
  const int t = threadIdx.x;
  const int lane = t & 63;
  const int wv = t >> 6;
  const int wr = wv >> 1, wc = wv & 1;
  const int tiles_n = N >> 7;
  const int bm = blockIdx.x / tiles_n, bn = blockIdx.x % tiles_n;

  const unsigned short* Ag = A + (size_t)bm * 128 * K;
  const unsigned short* Wg = W + (size_t)bn * 128 * K;

  f32x4 acc[4][4];
  #pragma unroll
  for (int i = 0; i < 4; i++)
    #pragma unroll
    for (int j = 0; j < 4; j++) acc[i][j] = (f32x4){0.f, 0.f, 0.f, 0.f};

  const int r = lane & 15, kg = lane >> 4;

  for (int kt = 0; kt < K; kt += 32){
    #pragma unroll
    for (int j = 0; j < 2; j++){
      int c = j * 256 + t;
      int row = c >> 2, kc = c & 3;
      async16(Ag + (size_t)row * K + kt + kc * 8, &As8[c]);
      async16(Wg + (size_t)row * K + kt + kc * 8, &Bs8[c]);
    }
    __syncthreads();   // drains vmcnt(0) before barrier -> LDS tiles valid
    short8 af[4], bfr[4];
    #pragma unroll
    for (int mi = 0; mi < 4; mi++) af[mi] = As8[(wr * 64 + mi * 16 + r) * 4 + kg];
    #pragma unroll
    for (int ni = 0; ni < 4; ni++) bfr[ni] = Bs8[(wc * 64 + ni * 16 + r) * 4 + kg];
    #pragma unroll
    for (int mi = 0; mi < 4; mi++)
      #pragma unroll
      for (int ni = 0; ni < 4; ni++)
        acc[mi][ni] = __builtin_amdgcn_mfma_f32_16x16x32_bf16(af[mi], bfr[ni], acc[mi][ni], 0, 0, 0);
    __syncthreads();   // all reads done before next stage overwrites
  }

  const size_t m0 = (size_t)bm * 128 + wr * 64;
  const size_t n0 = (size_t)bn * 128 + wc * 64;
  #pragma unroll
  for (int mi = 0; mi < 4; mi++){
    #pragma unroll
    for (int ni = 0; ni < 4; ni++){
      size_t row = m0 + mi * 16 + kg * 4;
      size_t col = n0 + ni * 16 + r;
      float bv = bias[col];
      #pragma unroll
      for (int rg = 0; rg < 4; rg++){
        float val = acc[mi][ni][rg] + bv;
        if (OUT_BF16) ((unsigned short*)Cout)[(row + rg) * N + col] = f2bf(val);
        else          ((float*)Cout)[(row + rg) * N + col] = val;
      }
    }
  }
}

// ---------------------------------------------------------------- depthwise pool q (2x2 s2)
__global__ __launch_bounds__(256)
void pool_q_kernel(const unsigned short* __restrict__ qkv, const float* __restrict__ wq,
                   float* __restrict__ out)
{
  const int bid = blockIdx.x;            // 192*28
  const int bh = bid / 28, oy = bid % 28;
  const int b = bh / 12, h = bh % 12;
  __shared__ unsigned short in[112 * 66];   // (y,x) slices, pitch 66
  const int t = threadIdx.x;
  for (int i = t; i < 112 * 32; i += 256){
    int slice = i >> 5, c2 = i & 31;
    int y = slice / 56, x = slice - y * 56;
    size_t ge = ((size_t)(b * 3136 + (2 * oy + y) * 56 + x)) * 2304 + (size_t)h * 64 + c2 * 2;
    *(unsigned int*)&in[slice * 66 + c2 * 2] = *(const unsigned int*)&qkv[ge];
  }
  __syncthreads();
  for (int o = t; o < 64 * 28; o += 256){
    int c = o / 28, ox = o - (o / 28) * 28;
    float w0 = wq[c * 4 + 0], w1 = wq[c * 4 + 1], w2 = wq[c * 4 + 2], w3 = wq[c * 4 + 3];
    int x0 = 2 * ox;
    float acc = bf2f(in[(x0    ) * 66 + c]) * w0 + bf2f(in[(x0 + 1     ) * 66 + c]) * w1
              + bf2f(in[(56 + x0) * 66 + c]) * w2 + bf2f(in[(56 + x0 + 1) * 66 + c]) * w3;
    out[(size_t)bh * 50176 + c * 784 + oy * 28 + ox] = acc;
  }
}

// ---------------------------------------------------------------- depthwise pool k (4x4 s4)
__global__ __launch_bounds__(256)
void pool_k_kernel(const unsigned short* __restrict__ qkv, const float* __restrict__ wk,
                   float* __restrict__ out)
{
  const int bid = blockIdx.x;            // 192*14
  const int bh = bid / 14, oy = bid % 14;
  const int b = bh / 12, h = bh % 12;
  __shared__ unsigned short in[224 * 66];
  const int t = threadIdx.x;
  for (int i = t; i < 224 * 32; i += 256){
    int slice = i >> 5, c2 = i & 31;
    int y = slice / 56, x = slice - y * 56;
    size_t ge = ((size_t)(b * 3136 + (4 * oy + y) * 56 + x)) * 2304 + 768 + (size_t)h * 64 + c2 * 2;
    *(unsigned int*)&in[slice * 66 + c2 * 2] = *(const unsigned int*)&qkv[ge];
  }
  __syncthreads();
  for (int o = t; o < 64 * 14; o += 256){
    int c = o / 14, ox = o % 14;
    float acc = 0.f;
    #pragma unroll
    for (int i2 = 0; i2 < 4; i2++)
      #pragma unroll
      for (int j2 = 0; j2 < 4; j2++)
        acc += bf2f(in[(i2 * 56 + 4 * ox + j2) * 66 + c]) * wk[c * 16 + i2 * 4 + j2];
    out[(size_t)bh * 12544 + c * 196 + oy * 14 + ox] = acc;
  }
}

// ---------------------------------------------------------------- full conv pool v via MFMA
// per block (bh, oy): out[dv][ox] = sum_k patch[ox][k] * Wv[dv][k], k = ij*64+c, K=1024
__global__ __launch_bounds__(256)
void pool_v_kernel(const unsigned short* __restrict__ qkv, const unsigned short* __restrict__ wvb,
                   float* __restrict__ out)
{
  const int bid = blockIdx.x;            // 192*14
  const int bh = bid / 14, oy = bid % 14;
  const int b = bh / 12, h = bh % 12;
  __shared__ __align__(16) unsigned short in[224 * 72];   // pitch 72 (16B-aligned rows)
  const int t = threadIdx.x, lane = t & 63, w = t >> 6;

  for (int i = t; i < 224 * 32; i += 256){
    int slice = i >> 5, c2 = i & 31;
    int y = slice / 56, x = slice - y * 56;
    size_t ge = ((size_t)(b * 3136 + (4 * oy + y) * 56 + x)) * 2304 + 1536 + (size_t)h * 64 + c2 * 2;
    *(unsigned int*)&in[slice * 72 + c2 * 2] = *(const unsigned int*)&qkv[ge];
  }
  __syncthreads();

  const int r = lane & 15, kg = lane >> 4;
  const int ox = r;                       // A-row: output spatial (valid < 14)
  const int dv = w * 16 + r;              // B-col: output channel
  f32x4 acc = (f32x4){0.f, 0.f, 0.f, 0.f};
  #pragma unroll 4
  for (int kt = 0; kt < 1024; kt += 32){
    int k0 = kt + kg * 8;
    int ij = k0 >> 6, c0 = k0 & 63;
    int i2 = ij >> 2, j2 = ij & 3;
    short8 af = {0, 0, 0, 0, 0, 0, 0, 0};
    if (ox < 14) af = *(const short8*)&in[(i2 * 56 + 4 * ox + j2) * 72 + c0];
    short8 bfr = *(const short8*)&wvb[(size_t)dv * 1024 + k0];
    acc = __builtin_amdgcn_mfma_f32_16x16x32_bf16(af, bfr, acc, 0, 0, 0);
  }
  #pragma unroll
  for (int rg = 0; rg < 4; rg++){
    int oxr = kg * 4 + rg;
    if (oxr < 14)
      out[(size_t)bh * 12544 + dv * 196 + oy * 14 + oxr] = acc[rg];
  }
}

// ---------------------------------------------------------------- fused attention (f32), out bf16 at (b, n, h*64+d)
__global__ __launch_bounds__(256)
void attn_kernel(const float* __restrict__ q, const float* __restrict__ k,
                 const float* __restrict__ v, unsigned short* __restrict__ out)
{
  const int bid = blockIdx.x;           // 192*49
  const int bh = bid / 49, qt = bid % 49;
  const int b = bh / 12, h = bh % 12;
  __shared__ float Ks[196 * 80];        // pitch 80: aligned f32x4, 2-way-free banks
  __shared__ float Vs[196 * 64];
  __shared__ float Qs[16 * 64];
  __shared__ float Ps[16 * 200];
  const int t = threadIdx.x, lane = t & 63, w = t >> 6;

  const float* kb = k + (size_t)bh * 12544;
  const float* vb = v + (size_t)bh * 12544;
  for (int i = t; i < 12544; i += 256){
    int m = i >> 6, d = i & 63;
    Ks[m * 80 + d] = kb[i];
    Vs[i] = vb[i];
  }
  const float* qb = q + (size_t)bh * 50176 + (size_t)qt * 1024;
  for (int i = t; i < 1024; i += 256) Qs[i] = qb[i] * 0.125f;
  if (t < 64) Ps[(t >> 2) * 200 + 196 + (t & 3)] = 0.f;
  __syncthreads();

  float inv[4];
  for (int rr = 0; rr < 4; rr++){
    const int lr = w * 4 + rr;
    float s[4];
    float mx = -1e30f;
    #pragma unroll
    for (int u = 0; u < 4; u++){
      int m = lane + 64 * u;
      s[u] = -1e30f;
      if (m < 196){
        const float* kr = &Ks[m * 80];
        const float* qr = &Qs[lr * 64];
        float acc = 0.f;
        #pragma unroll
        for (int kk = 0; kk < 64; kk += 4){
          f32x4 qv = *(const f32x4*)&qr[kk];
          f32x4 kv = *(const f32x4*)&kr[kk];
          acc += qv[0]*kv[0] + qv[1]*kv[1] + qv[2]*kv[2] + qv[3]*kv[3];
        }
        s[u] = acc;
        mx = fmaxf(mx, acc);
      }
    }
    mx = wmax(mx);
    float sum = 0.f;
    #pragma unroll
    for (int u = 0; u < 4; u++){
      int m = lane + 64 * u;
      if (m < 196){
        float p = __expf(s[u] - mx);
        Ps[lr * 200 + m] = p;
        sum += p;
      }
    }
    sum = wsum(sum);
    inv[rr] = 1.f / sum;
  }
  // PV: 4 rows jointly (wave-private Ps rows; in-wave LDS ordering handled by compiler)
  float o0 = 0.f, o1 = 0.f, o2 = 0.f, o3 = 0.f;
  const int p0 = (w * 4 + 0) * 200, p1 = (w * 4 + 1) * 200;
  const int p2 = (w * 4 + 2) * 200, p3 = (w * 4 + 3) * 200;
  for (int m = 0; m < 196; m += 4){
    f32x4 a0 = *(const f32x4*)&Ps[p0 + m];
    f32x4 a1 = *(const f32x4*)&Ps[p1 + m];
    f32x4 a2 = *(const f32x4*)&Ps[p2 + m];
    f32x4 a3 = *(const f32x4*)&Ps[p3 + m];
    #pragma unroll
    for (int i = 0; i < 4; i++){
      float vv = Vs[(m + i) * 64 + lane];
      o0 += a0[i] * vv; o1 += a1[i] * vv; o2 += a2[i] * vv; o3 += a3[i] * vv;
    }
  }
  const size_t ob = ((size_t)b * 784 + qt * 16 + w * 4) * 768 + h * 64 + lane;
  out[ob       ] = f2bf(o0 * inv[0]);
  out[ob +  768] = f2bf(o1 * inv[1]);
  out[ob + 1536] = f2bf(o2 * inv[2]);
  out[ob + 2304] = f2bf(o3 * inv[3]);
}

// ---------------------------------------------------------------- launch
extern "C" void kernel_launch(void* const* d_in, const int* in_sizes, int n_in,
                              void* d_out, int out_size, void* d_ws, size_t ws_size,
                              hipStream_t stream)
{
  (void)in_sizes; (void)n_in; (void)out_size; (void)ws_size;
  const float* x      = (const float*)d_in[0];
  const float* norm_w = (const float*)d_in[3];
  const float* norm_b = (const float*)d_in[4];
  const float* qkv_w  = (const float*)d_in[5];
  const float* qkv_b  = (const float*)d_in[6];
  const float* pq_w   = (const float*)d_in[7];
  const float* pk_w   = (const float*)d_in[8];
  const float* pv_w   = (const float*)d_in[9];
  const float* nq_w   = (const float*)d_in[10];
  const float* nq_b   = (const float*)d_in[11];
  const float* nk_w   = (const float*)d_in[12];
  const float* nk_b   = (const float*)d_in[13];
  const float* nv_w   = (const float*)d_in[14];
  const float* nv_b   = (const float*)d_in[15];
  const float* proj_w = (const float*)d_in[16];
  const float* proj_b = (const float*)d_in[17];
  float* outp = (float*)d_out;

  char* ws = (char*)d_ws;
  size_t o = 0;
  unsigned short* wqkv16  = (unsigned short*)(ws + o); o += 3538944;    // 2304*768 bf16
  unsigned short* wproj16 = (unsigned short*)(ws + o); o += 1179648;    // 768*768 bf16
  unsigned short* wv16    = (unsigned short*)(ws + o); o += 131072;     // 64*1024 bf16 (reordered)
  unsigned short* xn      = (unsigned short*)(ws + o); o += 77070336;   // 50176*768 bf16
  unsigned short* qkv     = (unsigned short*)(ws + o); o += 231211008;  // 50176*2304 bf16
  float*  qpool           = (float*)(ws + o);          o += 38535168;   // 192*50176 f32
  float*  kpool           = (float*)(ws + o);          o += 9633792;    // 192*12544 f32
  float*  vpool           = (float*)(ws + o);          o += 9633792;
  unsigned short* attno   = (unsigned short*)(ws + o); o += 19267584;   // 12544*768 bf16

  tobf16_kernel<<<(1769472 + 255) / 256, 256, 0, stream>>>(qkv_w, wqkv16, 1769472);
  tobf16_kernel<<<(589824 + 255) / 256, 256, 0, stream>>>(proj_w, wproj16, 589824);
  conv_wv_kernel<<<256, 256, 0, stream>>>(pv_w, wv16);

  ln768_kernel<<<12544, 256, 0, stream>>>(x, norm_w, norm_b, xn);

  gemm_bt<1><<<392 * 18, 256, 0, stream>>>(xn, wqkv16, qkv_b, qkv, 50176, 2304, 768);

  pool_q_kernel<<<192 * 28, 256, 0, stream>>>(qkv, pq_w, qpool);
  pool_k_kernel<<<192 * 14, 256, 0, stream>>>(qkv, pk_w, kpool);
  pool_v_kernel<<<192 * 14, 256, 0, stream>>>(qkv, wv16, vpool);

  ln64_kernel<<<150528 / 4, 256, 0, stream>>>(qpool, nq_w, nq_b, 1e-5f);
  ln64_kernel<<<37632 / 4, 256, 0, stream>>>(kpool, nk_w, nk_b, 1e-5f);
  ln64_kernel<<<37632 / 4, 256, 0, stream>>>(vpool, nv_w, nv_b, 1e-5f);

  attn_kernel<<<192 * 49, 256, 0, stream>>>(qpool, kpool, vpool, attno);

  gemm_bt<0><<<98 * 6, 256, 0, stream>>>(attno, wproj16, proj_b, outp, 12544, 768, 768);
}

// Round 2
// 550.131 us; speedup vs baseline: 1.9596x; 1.9596x over previous
//
#include <hip/hip_runtime.h>
#include <hip/hip_bf16.h>

using short8 = __attribute__((ext_vector_type(8))) short;
using f32x4  = __attribute__((ext_vector_type(4))) float;

#define DEVI __device__ __forceinline__
#define SWZ(byte, row) ((unsigned)(byte) ^ ((((unsigned)(row)) & 7u) << 4))

DEVI unsigned short f2bf(float f){
  unsigned int u = __float_as_uint(f);
  unsigned int r = (u + 0x7fffu + ((u >> 16) & 1u)) >> 16;
  return (unsigned short)r;
}
DEVI float bf2f(unsigned short u){ return __uint_as_float(((unsigned int)u) << 16); }

DEVI float wsum(float x){
  #pragma unroll
  for (int o = 32; o > 0; o >>= 1) x += __shfl_xor(x, o, 64);
  return x;
}

DEVI void async16(const void* g, void* l){
  __builtin_amdgcn_global_load_lds(
      (const __attribute__((address_space(1))) void*)g,
      (__attribute__((address_space(3))) void*)l,
      16, 0, 0);
}

// ---------------------------------------------------------------- weight casts
__global__ void tobf16_kernel(const float* __restrict__ in, unsigned short* __restrict__ out, int n){
  int i = blockIdx.x * 256 + threadIdx.x;
  if (i < n) out[i] = f2bf(in[i]);
}

// pool_v_w (dv, c, 4, 4) f32 -> wvb[dv][ij*64 + c] bf16  (k = ij*64 + c)
__global__ void conv_wv_kernel(const float* __restrict__ wv, unsigned short* __restrict__ wvb){
  int i = blockIdx.x * 256 + threadIdx.x;   // 64*64*16 = 65536
  if (i >= 65536) return;
  int dv = i >> 10, c = (i >> 4) & 63, ij = i & 15;
  wvb[dv * 1024 + ij * 64 + c] = f2bf(wv[i]);
}

// ---------------------------------------------------------------- LN over 768, f32 in -> bf16 out
__global__ __launch_bounds__(256)
void ln768_kernel(const float* __restrict__ x, const float* __restrict__ w,
                  const float* __restrict__ b, unsigned short* __restrict__ out)
{
  const int row  = blockIdx.x * 4 + (threadIdx.x >> 6);
  const int lane = threadIdx.x & 63;
  const float* xr = x + (size_t)row * 768;
  f32x4 v[3];
  float s = 0.f, s2 = 0.f;
  #pragma unroll
  for (int kk = 0; kk < 3; kk++){
    v[kk] = *(const f32x4*)&xr[lane * 4 + kk * 256];
    #pragma unroll
    for (int e = 0; e < 4; e++){ s += v[kk][e]; s2 += v[kk][e] * v[kk][e]; }
  }
  s = wsum(s); s2 = wsum(s2);
  float mu  = s * (1.f / 768.f);
  float var = s2 * (1.f / 768.f) - mu * mu;
  float rs  = rsqrtf(var + 1e-6f);
  unsigned short* orow = out + (size_t)row * 768;
  #pragma unroll
  for (int kk = 0; kk < 3; kk++){
    int c0 = lane * 4 + kk * 256;
    float y0 = (v[kk][0] - mu) * rs * w[c0 + 0] + b[c0 + 0];
    float y1 = (v[kk][1] - mu) * rs * w[c0 + 1] + b[c0 + 1];
    float y2 = (v[kk][2] - mu) * rs * w[c0 + 2] + b[c0 + 2];
    float y3 = (v[kk][3] - mu) * rs * w[c0 + 3] + b[c0 + 3];
    unsigned int lo = (unsigned int)f2bf(y0) | ((unsigned int)f2bf(y1) << 16);
    unsigned int hi = (unsigned int)f2bf(y2) | ((unsigned int)f2bf(y3) << 16);
    *(uint2*)&orow[c0] = make_uint2(lo, hi);
  }
}

// ---------------------------------------------------------------- LN64 -> bf16 Q (scale folded)
__global__ __launch_bounds__(256)
void ln64q_kernel(const float* __restrict__ in, const float* __restrict__ w,
                  const float* __restrict__ b, unsigned short* __restrict__ out)
{
  const size_t chunk = (size_t)blockIdx.x * 4 + (threadIdx.x >> 6);
  const int lane = threadIdx.x & 63;
  float xv = in[chunk * 64 + lane];
  float mu = wsum(xv) * (1.f / 64.f);
  float dl = xv - mu;
  float var = wsum(dl * dl) * (1.f / 64.f);
  float y = dl * rsqrtf(var + 1e-5f) * w[lane] + b[lane];
  out[chunk * 64 + lane] = f2bf(y * 0.125f);
}

// ---------------------------------------------------------------- LN64 -> swizzled Kb tile
__global__ __launch_bounds__(256)
void ln64k_kernel(const float* __restrict__ in, const float* __restrict__ w,
                  const float* __restrict__ b, unsigned short* __restrict__ Kb)
{
  const int chunk = blockIdx.x * 4 + (threadIdx.x >> 6);   // 192*196
  const int lane = threadIdx.x & 63;
  const int bh = chunk / 196, m = chunk % 196;
  float xv = in[(size_t)chunk * 64 + lane];
  float mu = wsum(xv) * (1.f / 64.f);
  float dl = xv - mu;
  float var = wsum(dl * dl) * (1.f / 64.f);
  float y = dl * rsqrtf(var + 1e-5f) * w[lane] + b[lane];
  char* og = (char*)Kb + (size_t)bh * 26624;
  *(unsigned short*)(og + SWZ(m * 128 + lane * 2, m)) = f2bf(y);
}

// ---------------------------------------------------------------- LN64 + transpose -> swizzled Vt tile
__global__ __launch_bounds__(256)
void vt_prep_kernel(const float* __restrict__ vpool, const float* __restrict__ w,
                    const float* __restrict__ b, unsigned short* __restrict__ Vtb)
{
  const int bh = blockIdx.x;                 // 192
  __shared__ float Ls[196 * 65];
  const float* vb = vpool + (size_t)bh * 12544;
  const int t = threadIdx.x, lane = t & 63, wv = t >> 6;
  for (int i = t; i < 12544; i += 256){
    int n = i >> 6, d = i & 63;
    Ls[n * 65 + d] = vb[i];
  }
  __syncthreads();
  for (int n = wv; n < 196; n += 4){
    float xv = Ls[n * 65 + lane];
    float mu = wsum(xv) * (1.f / 64.f);
    float dl = xv - mu;
    float var = wsum(dl * dl) * (1.f / 64.f);
    Ls[n * 65 + lane] = dl * rsqrtf(var + 1e-5f) * w[lane] + b[lane];
  }
  __syncthreads();
  char* og = (char*)Vtb + (size_t)bh * 26624;
  for (int j = t; j < 12544; j += 256){
    int d = j / 196, n = j % 196;
    *(unsigned short*)(og + SWZ(d * 416 + n * 2, d)) = f2bf(Ls[n * 65 + d]);
  }
  for (int j = t; j < 768; j += 256){        // zero pads n=196..207 (NaN-safe PV)
    int d = j / 12, n = 196 + j % 12;
    *(unsigned short*)(og + SWZ(d * 416 + n * 2, d)) = 0;
  }
}

// ---------------------------------------------------------------- 128x128 MFMA bf16 B^T GEMM
template <int OUT_BF16>
__global__ __launch_bounds__(256, 2)
void gemm_bt(const unsigned short* __restrict__ A, const unsigned short* __restrict__ W,
             const float* __restrict__ bias, void* __restrict__ Cout,
             int M, int N, int K)
{
  __shared__ short8 As8[512];   // 128 rows x 32 bf16
  __shared__ short8 Bs8[512];
  const int t = threadIdx.x;
  const int lane = t & 63;
  const int wv = t >> 6;
  const int wr = wv >> 1, wc = wv & 1;
  const int tiles_n = N >> 7;
  const int bm = blockIdx.x / tiles_n, bn = blockIdx.x % tiles_n;

  const unsigned short* Ag = A + (size_t)bm * 128 * K;
  const unsigned short* Wg = W + (size_t)bn * 128 * K;

  f32x4 acc[4][4];
  #pragma unroll
  for (int i = 0; i < 4; i++)
    #pragma unroll
    for (int j = 0; j < 4; j++) acc[i][j] = (f32x4){0.f, 0.f, 0.f, 0.f};

  const int r = lane & 15, kg = lane >> 4;

  for (int kt = 0; kt < K; kt += 32){
    #pragma unroll
    for (int j = 0; j < 2; j++){
      int c = j * 256 + t;
      int row = c >> 2, kc = c & 3;
      async16(Ag + (size_t)row * K + kt + kc * 8, &As8[c]);
      async16(Wg + (size_t)row * K + kt + kc * 8, &Bs8[c]);
    }
    __syncthreads();
    short8 af[4], bfr[4];
    #pragma unroll
    for (int mi = 0; mi < 4; mi++) af[mi] = As8[(wr * 64 + mi * 16 + r) * 4 + kg];
    #pragma unroll
    for (int ni = 0; ni < 4; ni++) bfr[ni] = Bs8[(wc * 64 + ni * 16 + r) * 4 + kg];
    #pragma unroll
    for (int mi = 0; mi < 4; mi++)
      #pragma unroll
      for (int ni = 0; ni < 4; ni++)
        acc[mi][ni] = __builtin_amdgcn_mfma_f32_16x16x32_bf16(af[mi], bfr[ni], acc[mi][ni], 0, 0, 0);
    __syncthreads();
  }

  const size_t m0 = (size_t)bm * 128 + wr * 64;
  const size_t n0 = (size_t)bn * 128 + wc * 64;
  #pragma unroll
  for (int mi = 0; mi < 4; mi++){
    #pragma unroll
    for (int ni = 0; ni < 4; ni++){
      size_t row = m0 + mi * 16 + kg * 4;
      size_t col = n0 + ni * 16 + r;
      float bv = bias[col];
      #pragma unroll
      for (int rg = 0; rg < 4; rg++){
        float val = acc[mi][ni][rg] + bv;
        if (OUT_BF16) ((unsigned short*)Cout)[(row + rg) * N + col] = f2bf(val);
        else          ((float*)Cout)[(row + rg) * N + col] = val;
      }
    }
  }
}

// ---------------------------------------------------------------- depthwise pool q (2x2 s2)
__global__ __launch_bounds__(256)
void pool_q_kernel(const unsigned short* __restrict__ qkv, const float* __restrict__ wq,
                   float* __restrict__ out)
{
  const int bid = blockIdx.x;            // 192*28
  const int bh = bid / 28, oy = bid % 28;
  const int b = bh / 12, h = bh % 12;
  __shared__ unsigned short in[112 * 66];
  const int t = threadIdx.x;
  for (int i = t; i < 112 * 32; i += 256){
    int slice = i >> 5, c2 = i & 31;
    int y = slice / 56, x = slice - y * 56;
    size_t ge = ((size_t)(b * 3136 + (2 * oy + y) * 56 + x)) * 2304 + (size_t)h * 64 + c2 * 2;
    *(unsigned int*)&in[slice * 66 + c2 * 2] = *(const unsigned int*)&qkv[ge];
  }
  __syncthreads();
  for (int o = t; o < 64 * 28; o += 256){
    int c = o / 28, ox = o - (o / 28) * 28;
    float w0 = wq[c * 4 + 0], w1 = wq[c * 4 + 1], w2 = wq[c * 4 + 2], w3 = wq[c * 4 + 3];
    int x0 = 2 * ox;
    float acc = bf2f(in[(x0    ) * 66 + c]) * w0 + bf2f(in[(x0 + 1     ) * 66 + c]) * w1
              + bf2f(in[(56 + x0) * 66 + c]) * w2 + bf2f(in[(56 + x0 + 1) * 66 + c]) * w3;
    out[(size_t)bh * 50176 + c * 784 + oy * 28 + ox] = acc;
  }
}

// ---------------------------------------------------------------- depthwise pool k (4x4 s4)
__global__ __launch_bounds__(256)
void pool_k_kernel(const unsigned short* __restrict__ qkv, const float* __restrict__ wk,
                   float* __restrict__ out)
{
  const int bid = blockIdx.x;            // 192*14
  const int bh = bid / 14, oy = bid % 14;
  const int b = bh / 12, h = bh % 12;
  __shared__ unsigned short in[224 * 66];
  const int t = threadIdx.x;
  for (int i = t; i < 224 * 32; i += 256){
    int slice = i >> 5, c2 = i & 31;
    int y = slice / 56, x = slice - y * 56;
    size_t ge = ((size_t)(b * 3136 + (4 * oy + y) * 56 + x)) * 2304 + 768 + (size_t)h * 64 + c2 * 2;
    *(unsigned int*)&in[slice * 66 + c2 * 2] = *(const unsigned int*)&qkv[ge];
  }
  __syncthreads();
  for (int o = t; o < 64 * 14; o += 256){
    int c = o / 14, ox = o % 14;
    float acc = 0.f;
    #pragma unroll
    for (int i2 = 0; i2 < 4; i2++)
      #pragma unroll
      for (int j2 = 0; j2 < 4; j2++)
        acc += bf2f(in[(i2 * 56 + 4 * ox + j2) * 66 + c]) * wk[c * 16 + i2 * 4 + j2];
    out[(size_t)bh * 12544 + c * 196 + oy * 14 + ox] = acc;
  }
}

// ---------------------------------------------------------------- full conv pool v via MFMA
__global__ __launch_bounds__(256)
void pool_v_kernel(const unsigned short* __restrict__ qkv, const unsigned short* __restrict__ wvb,
                   float* __restrict__ out)
{
  const int bid = blockIdx.x;            // 192*14
  const int bh = bid / 14, oy = bid % 14;
  const int b = bh / 12, h = bh % 12;
  __shared__ __align__(16) unsigned short in[224 * 72];
  const int t = threadIdx.x, lane = t & 63, w = t >> 6;

  for (int i = t; i < 224 * 32; i += 256){
    int slice = i >> 5, c2 = i & 31;
    int y = slice / 56, x = slice - y * 56;
    size_t ge = ((size_t)(b * 3136 + (4 * oy + y) * 56 + x)) * 2304 + 1536 + (size_t)h * 64 + c2 * 2;
    *(unsigned int*)&in[slice * 72 + c2 * 2] = *(const unsigned int*)&qkv[ge];
  }
  __syncthreads();

  const int r = lane & 15, kg = lane >> 4;
  const int ox = r;
  const int dv = w * 16 + r;
  f32x4 acc = (f32x4){0.f, 0.f, 0.f, 0.f};
  #pragma unroll 4
  for (int kt = 0; kt < 1024; kt += 32){
    int k0 = kt + kg * 8;
    int ij = k0 >> 6, c0 = k0 & 63;
    int i2 = ij >> 2, j2 = ij & 3;
    short8 af = {0, 0, 0, 0, 0, 0, 0, 0};
    if (ox < 14) af = *(const short8*)&in[(i2 * 56 + 4 * ox + j2) * 72 + c0];
    short8 bfr = *(const short8*)&wvb[(size_t)dv * 1024 + k0];
    acc = __builtin_amdgcn_mfma_f32_16x16x32_bf16(af, bfr, acc, 0, 0, 0);
  }
  #pragma unroll
  for (int rg = 0; rg < 4; rg++){
    int oxr = kg * 4 + rg;
    if (oxr < 14)
      out[(size_t)bh * 12544 + dv * 196 + oy * 14 + oxr] = acc[rg];
  }
}

// ---------------------------------------------------------------- MFMA fused attention
// block = (bh, 64-q-row tile); 4 waves x 16 q-rows. K_lds/Vt_lds swizzled tiles.
__global__ __launch_bounds__(256)
void attn2_kernel(const unsigned short* __restrict__ Qb, const unsigned short* __restrict__ Kb,
                  const unsigned short* __restrict__ Vtb, unsigned short* __restrict__ out)
{
  const int bid = blockIdx.x;            // 192*13
  const int bh = bid / 13, qt = bid % 13;
  const int b = bh / 12, h = bh % 12;
  __shared__ __align__(128) char K_lds[26624];   // 208x64 bf16, row-swizzled
  __shared__ __align__(128) char V_lds[26624];   // 64x208 bf16 (V^T), row-swizzled
  __shared__ __align__(128) char P_lds[26624];   // 64x208 bf16, row-swizzled
  const int t = threadIdx.x, lane = t & 63, w = t >> 6;
  const int r = lane & 15, kg = lane >> 4;
  const short8 z8 = {0, 0, 0, 0, 0, 0, 0, 0};

  const char* Kg = (const char*)Kb + (size_t)bh * 26624;
  const char* Vg = (const char*)Vtb + (size_t)bh * 26624;
  #pragma unroll
  for (int i = 0; i < 7; i++){
    int j = i * 256 + t;
    if (j < 1664) async16(Kg + j * 16, K_lds + j * 16);
  }
  #pragma unroll
  for (int i = 0; i < 7; i++){
    int j = i * 256 + t;
    if (j < 1664) async16(Vg + j * 16, V_lds + j * 16);
  }

  // Q fragments straight from global bf16 (rows beyond 784 are slack, never stored)
  const size_t qrow = (size_t)bh * 784 + qt * 64 + w * 16 + r;
  short8 aq0 = *(const short8*)&Qb[qrow * 64 + kg * 8];
  short8 aq1 = *(const short8*)&Qb[qrow * 64 + 32 + kg * 8];

  __syncthreads();   // vmcnt(0) drained before barrier -> tiles valid

  // ---- QK^T: S[q_local][k] frags, row = kg*4+rg, col = k-frag col r
  f32x4 s[13];
  #pragma unroll
  for (int nf = 0; nf < 13; nf++){
    int row = nf * 16 + r;
    short8 bk0 = *(const short8*)(K_lds + SWZ(row * 128 + kg * 16, row));
    short8 bk1 = *(const short8*)(K_lds + SWZ(row * 128 + 64 + kg * 16, row));
    f32x4 a = (f32x4){0.f, 0.f, 0.f, 0.f};
    a = __builtin_amdgcn_mfma_f32_16x16x32_bf16(aq0, bk0, a, 0, 0, 0);
    a = __builtin_amdgcn_mfma_f32_16x16x32_bf16(aq1, bk1, a, 0, 0, 0);
    s[nf] = a;
  }

  // ---- mask pad cols (k >= 196): frag 12, col r >= 4
  #pragma unroll
  for (int rg = 0; rg < 4; rg++) if (r >= 4) s[12][rg] = -1e30f;

  // ---- wave-parallel softmax; P -> LDS (bf16, unnormalized), inv kept in regs
  float inv[4];
  #pragma unroll
  for (int rg = 0; rg < 4; rg++){
    float m0 = s[0][rg];
    #pragma unroll
    for (int nf = 1; nf < 13; nf++) m0 = fmaxf(m0, s[nf][rg]);
    m0 = fmaxf(m0, __shfl_xor(m0, 1, 64));
    m0 = fmaxf(m0, __shfl_xor(m0, 2, 64));
    m0 = fmaxf(m0, __shfl_xor(m0, 4, 64));
    m0 = fmaxf(m0, __shfl_xor(m0, 8, 64));
    const int q = w * 16 + kg * 4 + rg;
    float sum = 0.f;
    #pragma unroll
    for (int nf = 0; nf < 13; nf++){
      float p = __expf(s[nf][rg] - m0);
      if (nf == 12 && r >= 4) p = 0.f;   // also NaN-safe for garbage pad K
      sum += p;
      *(unsigned short*)(P_lds + SWZ(q * 416 + (nf * 16 + r) * 2, q)) = f2bf(p);
    }
    sum += __shfl_xor(sum, 1, 64);
    sum += __shfl_xor(sum, 2, 64);
    sum += __shfl_xor(sum, 4, 64);
    sum += __shfl_xor(sum, 8, 64);
    inv[rg] = 1.f / sum;
  }

  // ---- PV: O[q_local][dv], per-wave rows only (no cross-wave dep, no barrier)
  f32x4 o[4];
  #pragma unroll
  for (int i = 0; i < 4; i++) o[i] = (f32x4){0.f, 0.f, 0.f, 0.f};
  const int qr = w * 16 + r;
  #pragma unroll
  for (int ks = 0; ks < 7; ks++){
    short8 ap = z8, bv0 = z8, bv1 = z8, bv2 = z8, bv3 = z8;
    if (ks < 6 || kg < 2){   // tail k 208..223 masked with zero frags
      ap  = *(const short8*)(P_lds + SWZ(qr * 416 + ks * 64 + kg * 16, qr));
      bv0 = *(const short8*)(V_lds + SWZ((0 * 16 + r) * 416 + ks * 64 + kg * 16, (0 * 16 + r)));
      bv1 = *(const short8*)(V_lds + SWZ((1 * 16 + r) * 416 + ks * 64 + kg * 16, (1 * 16 + r)));
      bv2 = *(const short8*)(V_lds + SWZ((2 * 16 + r) * 416 + ks * 64 + kg * 16, (2 * 16 + r)));
      bv3 = *(const short8*)(V_lds + SWZ((3 * 16 + r) * 416 + ks * 64 + kg * 16, (3 * 16 + r)));
    }
    o[0] = __builtin_amdgcn_mfma_f32_16x16x32_bf16(ap, bv0, o[0], 0, 0, 0);
    o[1] = __builtin_amdgcn_mfma_f32_16x16x32_bf16(ap, bv1, o[1], 0, 0, 0);
    o[2] = __builtin_amdgcn_mfma_f32_16x16x32_bf16(ap, bv2, o[2], 0, 0, 0);
    o[3] = __builtin_amdgcn_mfma_f32_16x16x32_bf16(ap, bv3, o[3], 0, 0, 0);
  }

  // ---- store (b, q_global, h*64 + dv) bf16
  #pragma unroll
  for (int rg = 0; rg < 4; rg++){
    int qg = qt * 64 + w * 16 + kg * 4 + rg;
    if (qg < 784){
      unsigned short* orow = out + ((size_t)b * 784 + qg) * 768 + h * 64;
      float sc = inv[rg];
      orow[ 0 + r] = f2bf(o[0][rg] * sc);
      orow[16 + r] = f2bf(o[1][rg] * sc);
      orow[32 + r] = f2bf(o[2][rg] * sc);
      orow[48 + r] = f2bf(o[3][rg] * sc);
    }
  }
}

// ---------------------------------------------------------------- launch
extern "C" void kernel_launch(void* const* d_in, const int* in_sizes, int n_in,
                              void* d_out, int out_size, void* d_ws, size_t ws_size,
                              hipStream_t stream)
{
  (void)in_sizes; (void)n_in; (void)out_size; (void)ws_size;
  const float* x      = (const float*)d_in[0];
  const float* norm_w = (const float*)d_in[3];
  const float* norm_b = (const float*)d_in[4];
  const float* qkv_w  = (const float*)d_in[5];
  const float* qkv_b  = (const float*)d_in[6];
  const float* pq_w   = (const float*)d_in[7];
  const float* pk_w   = (const float*)d_in[8];
  const float* pv_w   = (const float*)d_in[9];
  const float* nq_w   = (const float*)d_in[10];
  const float* nq_b   = (const float*)d_in[11];
  const float* nk_w   = (const float*)d_in[12];
  const float* nk_b   = (const float*)d_in[13];
  const float* nv_w   = (const float*)d_in[14];
  const float* nv_b   = (const float*)d_in[15];
  const float* proj_w = (const float*)d_in[16];
  const float* proj_b = (const float*)d_in[17];
  float* outp = (float*)d_out;

  char* ws = (char*)d_ws;
  size_t o = 0;
  unsigned short* wqkv16  = (unsigned short*)(ws + o); o += 3538944;    // 2304*768 bf16
  unsigned short* wproj16 = (unsigned short*)(ws + o); o += 1179648;    // 768*768 bf16
  unsigned short* wv16    = (unsigned short*)(ws + o); o += 131072;     // 64*1024 bf16
  char* xn_region         = (ws + o);                  o += 77070336;   // xn, later reused for Qb/Kb/Vtb
  unsigned short* qkv     = (unsigned short*)(ws + o); o += 231211008;  // 50176*2304 bf16
  float*  qpool           = (float*)(ws + o);          o += 38535168;   // 192*50176 f32
  float*  kpool           = (float*)(ws + o);          o += 9633792;    // 192*12544 f32
  float*  vpool           = (float*)(ws + o);          o += 9633792;
  unsigned short* attno   = (unsigned short*)(ws + o); o += 19267584;   // 12544*768 bf16

  unsigned short* xn  = (unsigned short*)xn_region;
  // overlays (xn dead after QKV GEMM): Qb 19275776 B, Kb 5111808 B, Vtb 5111808 B = 29.5 MB < 77 MB
  unsigned short* Qb  = (unsigned short*)xn_region;
  unsigned short* Kbt = (unsigned short*)(xn_region + 19275776);
  unsigned short* Vtb = (unsigned short*)(xn_region + 19275776 + 5111808);

  tobf16_kernel<<<(1769472 + 255) / 256, 256, 0, stream>>>(qkv_w, wqkv16, 1769472);
  tobf16_kernel<<<(589824 + 255) / 256, 256, 0, stream>>>(proj_w, wproj16, 589824);
  conv_wv_kernel<<<256, 256, 0, stream>>>(pv_w, wv16);

  ln768_kernel<<<12544, 256, 0, stream>>>(x, norm_w, norm_b, xn);

  gemm_bt<1><<<392 * 18, 256, 0, stream>>>(xn, wqkv16, qkv_b, qkv, 50176, 2304, 768);

  pool_q_kernel<<<192 * 28, 256, 0, stream>>>(qkv, pq_w, qpool);
  pool_k_kernel<<<192 * 14, 256, 0, stream>>>(qkv, pk_w, kpool);
  pool_v_kernel<<<192 * 14, 256, 0, stream>>>(qkv, wv16, vpool);

  ln64q_kernel<<<150528 / 4, 256, 0, stream>>>(qpool, nq_w, nq_b, Qb);
  ln64k_kernel<<<37632 / 4, 256, 0, stream>>>(kpool, nk_w, nk_b, Kbt);
  vt_prep_kernel<<<192, 256, 0, stream>>>(vpool, nv_w, nv_b, Vtb);

  attn2_kernel<<<192 * 13, 256, 0, stream>>>(Qb, Kbt, Vtb, attno);

  gemm_bt<0><<<98 * 6, 256, 0, stream>>>(attno, wproj16, proj_b, outp, 12544, 768, 768);
}

// Round 3
// 516.263 us; speedup vs baseline: 2.0882x; 1.0656x over previous
//
#include <hip/hip_runtime.h>
#include <hip/hip_bf16.h>

using short8 = __attribute__((ext_vector_type(8))) short;
using f32x4  = __attribute__((ext_vector_type(4))) float;

#define DEVI __device__ __forceinline__
#define SWZ(byte, row) ((unsigned)(byte) ^ ((((unsigned)(row)) & 7u) << 4))

DEVI unsigned short f2bf(float f){
  unsigned int u = __float_as_uint(f);
  unsigned int r = (u + 0x7fffu + ((u >> 16) & 1u)) >> 16;
  return (unsigned short)r;
}
DEVI float bf2f(unsigned short u){ return __uint_as_float(((unsigned int)u) << 16); }

DEVI float wsum(float x){
  #pragma unroll
  for (int o = 32; o > 0; o >>= 1) x += __shfl_xor(x, o, 64);
  return x;
}

DEVI void async16(const void* g, void* l){
  __builtin_amdgcn_global_load_lds(
      (const __attribute__((address_space(1))) void*)g,
      (__attribute__((address_space(3))) void*)l,
      16, 0, 0);
}

// ---------------------------------------------------------------- weight casts
__global__ void tobf16_kernel(const float* __restrict__ in, unsigned short* __restrict__ out, int n){
  int i = blockIdx.x * 256 + threadIdx.x;
  if (i < n) out[i] = f2bf(in[i]);
}

__global__ void conv_wv_kernel(const float* __restrict__ wv, unsigned short* __restrict__ wvb){
  int i = blockIdx.x * 256 + threadIdx.x;   // 64*64*16 = 65536
  if (i >= 65536) return;
  int dv = i >> 10, c = (i >> 4) & 63, ij = i & 15;
  wvb[dv * 1024 + ij * 64 + c] = f2bf(wv[i]);
}

// ---------------------------------------------------------------- LN over 768, f32 in -> bf16 out
__global__ __launch_bounds__(256)
void ln768_kernel(const float* __restrict__ x, const float* __restrict__ w,
                  const float* __restrict__ b, unsigned short* __restrict__ out)
{
  const int row  = blockIdx.x * 4 + (threadIdx.x >> 6);
  const int lane = threadIdx.x & 63;
  const float* xr = x + (size_t)row * 768;
  f32x4 v[3];
  float s = 0.f, s2 = 0.f;
  #pragma unroll
  for (int kk = 0; kk < 3; kk++){
    v[kk] = *(const f32x4*)&xr[lane * 4 + kk * 256];
    #pragma unroll
    for (int e = 0; e < 4; e++){ s += v[kk][e]; s2 += v[kk][e] * v[kk][e]; }
  }
  s = wsum(s); s2 = wsum(s2);
  float mu  = s * (1.f / 768.f);
  float var = s2 * (1.f / 768.f) - mu * mu;
  float rs  = rsqrtf(var + 1e-6f);
  unsigned short* orow = out + (size_t)row * 768;
  #pragma unroll
  for (int kk = 0; kk < 3; kk++){
    int c0 = lane * 4 + kk * 256;
    float y0 = (v[kk][0] - mu) * rs * w[c0 + 0] + b[c0 + 0];
    float y1 = (v[kk][1] - mu) * rs * w[c0 + 1] + b[c0 + 1];
    float y2 = (v[kk][2] - mu) * rs * w[c0 + 2] + b[c0 + 2];
    float y3 = (v[kk][3] - mu) * rs * w[c0 + 3] + b[c0 + 3];
    unsigned int lo = (unsigned int)f2bf(y0) | ((unsigned int)f2bf(y1) << 16);
    unsigned int hi = (unsigned int)f2bf(y2) | ((unsigned int)f2bf(y3) << 16);
    *(uint2*)&orow[c0] = make_uint2(lo, hi);
  }
}

// ---------------------------------------------------------------- LN64 -> bf16 Q (scale folded)
__global__ __launch_bounds__(256)
void ln64q_kernel(const float* __restrict__ in, const float* __restrict__ w,
                  const float* __restrict__ b, unsigned short* __restrict__ out)
{
  const size_t chunk = (size_t)blockIdx.x * 4 + (threadIdx.x >> 6);
  const int lane = threadIdx.x & 63;
  float xv = in[chunk * 64 + lane];
  float mu = wsum(xv) * (1.f / 64.f);
  float dl = xv - mu;
  float var = wsum(dl * dl) * (1.f / 64.f);
  float y = dl * rsqrtf(var + 1e-5f) * w[lane] + b[lane];
  out[chunk * 64 + lane] = f2bf(y * 0.125f);
}

// ---------------------------------------------------------------- LN64 -> swizzled Kb tile
__global__ __launch_bounds__(256)
void ln64k_kernel(const float* __restrict__ in, const float* __restrict__ w,
                  const float* __restrict__ b, unsigned short* __restrict__ Kb)
{
  const int chunk = blockIdx.x * 4 + (threadIdx.x >> 6);   // 192*196
  const int lane = threadIdx.x & 63;
  const int bh = chunk / 196, m = chunk % 196;
  float xv = in[(size_t)chunk * 64 + lane];
  float mu = wsum(xv) * (1.f / 64.f);
  float dl = xv - mu;
  float var = wsum(dl * dl) * (1.f / 64.f);
  float y = dl * rsqrtf(var + 1e-5f) * w[lane] + b[lane];
  char* og = (char*)Kb + (size_t)bh * 26624;
  *(unsigned short*)(og + SWZ(m * 128 + lane * 2, m)) = f2bf(y);
}

// ---------------------------------------------------------------- LN64 + transpose -> swizzled Vt tile
__global__ __launch_bounds__(256)
void vt_prep_kernel(const float* __restrict__ vpool, const float* __restrict__ w,
                    const float* __restrict__ b, unsigned short* __restrict__ Vtb)
{
  const int bh = blockIdx.x;                 // 192
  __shared__ float Ls[196 * 65];
  const float* vb = vpool + (size_t)bh * 12544;
  const int t = threadIdx.x, lane = t & 63, wv = t >> 6;
  for (int i = t; i < 12544; i += 256){
    int n = i >> 6, d = i & 63;
    Ls[n * 65 + d] = vb[i];
  }
  __syncthreads();
  for (int n = wv; n < 196; n += 4){
    float xv = Ls[n * 65 + lane];
    float mu = wsum(xv) * (1.f / 64.f);
    float dl = xv - mu;
    float var = wsum(dl * dl) * (1.f / 64.f);
    Ls[n * 65 + lane] = dl * rsqrtf(var + 1e-5f) * w[lane] + b[lane];
  }
  __syncthreads();
  char* og = (char*)Vtb + (size_t)bh * 26624;
  for (int j = t; j < 12544; j += 256){
    int d = j / 196, n = j % 196;
    *(unsigned short*)(og + SWZ(d * 416 + n * 2, d)) = f2bf(Ls[n * 65 + d]);
  }
  for (int j = t; j < 768; j += 256){        // zero pads n=196..207 (NaN-safe PV)
    int d = j / 12, n = 196 + j % 12;
    *(unsigned short*)(og + SWZ(d * 416 + n * 2, d)) = 0;
  }
}

// ---------------------------------------------------------------- 256x256 8-phase MFMA bf16 B^T GEMM
// C[m][n] = sum_k A[m][k]*W[n][k] + bias[n]; M%256==0, N%256==0, K = NT*64. bf16 out.
// LDS: A: [slot][ksub][256rows][32cols] (2x2x16KB), B same at +65536. 16B-chunk XOR swizzle.
#define BAR() __builtin_amdgcn_s_barrier()
#define LGKM0() do{ asm volatile("s_waitcnt lgkmcnt(0)" ::: "memory"); __builtin_amdgcn_sched_barrier(0); }while(0)
#define VMW(N)  do{ asm volatile("s_waitcnt vmcnt(" #N ")" ::: "memory"); __builtin_amdgcn_sched_barrier(0); }while(0)

#define STAGE(GB, LOFF, KT, KS) do { \
  const unsigned short* gp_ = (GB) + (size_t)(KT) * 64 + (KS) * 32; \
  _Pragma("unroll") for (int l_ = 0; l_ < 2; ++l_){ \
    int i_ = l_ * 512 + tid; int row_ = i_ >> 2; int gch_ = (i_ & 3) ^ ((row_ >> 1) & 3); \
    async16(gp_ + (size_t)row_ * Kd + gch_ * 8, lds + (LOFF) + i_ * 16); \
  } } while(0)

#define LDA4(MH, KS) do { \
  _Pragma("unroll") for (int mm_ = 0; mm_ < 4; ++mm_){ \
    int row_ = wr * 128 + (MH) * 64 + mm_ * 16 + r; \
    Af[mm_] = *(const short8*)(lds + aoff + (KS) * 16384 + row_ * 64 + ((kg ^ ((row_ >> 1) & 3)) * 16)); \
  } } while(0)

#define LDB4(KS) do { \
  _Pragma("unroll") for (int nn_ = 0; nn_ < 4; ++nn_){ \
    int row_ = wc * 64 + nn_ * 16 + r; \
    Bf[nn_] = *(const short8*)(lds + boff + (KS) * 16384 + row_ * 64 + ((kg ^ ((row_ >> 1) & 3)) * 16)); \
  } } while(0)

#define MFMA16(MH) do { \
  __builtin_amdgcn_s_setprio(1); \
  _Pragma("unroll") for (int mm_ = 0; mm_ < 4; ++mm_) \
    _Pragma("unroll") for (int nn_ = 0; nn_ < 4; ++nn_) \
      acc[(MH) * 4 + mm_][nn_] = __builtin_amdgcn_mfma_f32_16x16x32_bf16(Af[mm_], Bf[nn_], acc[(MH) * 4 + mm_][nn_], 0, 0, 0); \
  __builtin_amdgcn_s_setprio(0); \
  } while(0)

template <int NT>
__global__ __launch_bounds__(512, 2)
void gemm256(const unsigned short* __restrict__ A, const unsigned short* __restrict__ W,
             const float* __restrict__ bias, unsigned short* __restrict__ C,
             int M, int N)
{
  constexpr int Kd = NT * 64;
  __shared__ __align__(128) char lds[131072];
  const int tid = threadIdx.x;
  const int lane = tid & 63, w = tid >> 6;
  const int r = lane & 15, kg = lane >> 4;
  const int wr = w >> 2, wc = w & 3;

  // bijective XCD swizzle (m204)
  const int nwg = gridDim.x;
  const int lq = nwg >> 3, lr = nwg & 7;
  const int xcd = blockIdx.x & 7;
  const int wg = (xcd < lr ? xcd * (lq + 1) : lr * (lq + 1) + (xcd - lr) * lq) + (blockIdx.x >> 3);
  const int tiles_n = N >> 8;
  const int bm = wg / tiles_n, bn = wg % tiles_n;

  const unsigned short* Ag = A + (size_t)bm * 256 * Kd;
  const unsigned short* Wg = W + (size_t)bn * 256 * Kd;

  f32x4 acc[8][4];
  #pragma unroll
  for (int i = 0; i < 8; i++)
    #pragma unroll
    for (int j = 0; j < 4; j++) acc[i][j] = (f32x4){0.f, 0.f, 0.f, 0.f};

  // prologue: tile0 (both halves) + tile1 k0-halves; wait oldest 8 of 12
  STAGE(Ag, 0, 0, 0);
  STAGE(Wg, 65536, 0, 0);
  STAGE(Ag, 16384, 0, 1);
  STAGE(Wg, 65536 + 16384, 0, 1);
  STAGE(Ag, 32768, 1, 0);
  STAGE(Wg, 65536 + 32768, 1, 0);
  VMW(4); BAR();

  for (int t = 0; t < NT; ++t){
    const int slot = t & 1;
    const int aoff = slot * 32768;
    const int boff = 65536 + slot * 32768;
    const int sn1 = ((t + 1) & 1) * 32768;
    const bool st1 = (t + 1 < NT), st2 = (t + 2 < NT);
    short8 Af[4], Bf[4];

    // ph1: ksub0, mhalf0
    LDB4(0); LDA4(0, 0);
    if (st1) STAGE(Ag, sn1 + 16384, t + 1, 1);
    BAR(); LGKM0();
    MFMA16(0);
    BAR();
    // ph2: ksub0, mhalf1
    LDA4(1, 0);
    if (st1) STAGE(Wg, 65536 + sn1 + 16384, t + 1, 1);
    BAR(); LGKM0();
    MFMA16(1);
    BAR();
    // ph3: ksub1, mhalf0  (k0 halves of this slot now free -> stage t+2)
    LDB4(1); LDA4(0, 1);
    if (st2) STAGE(Ag, aoff, t + 2, 0);
    BAR(); LGKM0();
    MFMA16(0);
    BAR();
    // ph4: ksub1, mhalf1
    LDA4(1, 1);
    if (st2) STAGE(Wg, 65536 + aoff, t + 2, 0);
    BAR(); LGKM0();
    MFMA16(1);
    if (t < NT - 2) { VMW(4); }
    else if (t == NT - 2) { VMW(0); }
    BAR();
  }

  // epilogue
  const size_t gm0 = (size_t)bm * 256 + wr * 128;
  const size_t gn0 = (size_t)bn * 256 + wc * 64;
  float bv[4];
  #pragma unroll
  for (int n = 0; n < 4; n++) bv[n] = bias[gn0 + n * 16 + r];
  #pragma unroll
  for (int m = 0; m < 8; m++){
    const size_t row = gm0 + m * 16 + kg * 4;
    #pragma unroll
    for (int n = 0; n < 4; n++){
      const size_t col = gn0 + n * 16 + r;
      #pragma unroll
      for (int rg = 0; rg < 4; rg++)
        C[(row + rg) * N + col] = f2bf(acc[m][n][rg] + bv[n]);
    }
  }
}

// ---------------------------------------------------------------- 128x128 MFMA bf16 B^T GEMM (proj)
template <int OUT_BF16>
__global__ __launch_bounds__(256, 2)
void gemm_bt(const unsigned short* __restrict__ A, const unsigned short* __restrict__ W,
             const float* __restrict__ bias, void* __restrict__ Cout,
             int M, int N, int K)
{
  __shared__ short8 As8[512];
  __shared__ short8 Bs8[512];
  const int t = threadIdx.x;
  const int lane = t & 63;
  const int wv = t >> 6;
  const int wr = wv >> 1, wc = wv & 1;
  const int tiles_n = N >> 7;
  const int bm = blockIdx.x / tiles_n, bn = blockIdx.x % tiles_n;

  const unsigned short* Ag = A + (size_t)bm * 128 * K;
  const unsigned short* Wg = W + (size_t)bn * 128 * K;

  f32x4 acc[4][4];
  #pragma unroll
  for (int i = 0; i < 4; i++)
    #pragma unroll
    for (int j = 0; j < 4; j++) acc[i][j] = (f32x4){0.f, 0.f, 0.f, 0.f};

  const int r = lane & 15, kg = lane >> 4;

  for (int kt = 0; kt < K; kt += 32){
    #pragma unroll
    for (int j = 0; j < 2; j++){
      int c = j * 256 + t;
      int row = c >> 2, kc = c & 3;
      async16(Ag + (size_t)row * K + kt + kc * 8, &As8[c]);
      async16(Wg + (size_t)row * K + kt + kc * 8, &Bs8[c]);
    }
    __syncthreads();
    short8 af[4], bfr[4];
    #pragma unroll
    for (int mi = 0; mi < 4; mi++) af[mi] = As8[(wr * 64 + mi * 16 + r) * 4 + kg];
    #pragma unroll
    for (int ni = 0; ni < 4; ni++) bfr[ni] = Bs8[(wc * 64 + ni * 16 + r) * 4 + kg];
    #pragma unroll
    for (int mi = 0; mi < 4; mi++)
      #pragma unroll
      for (int ni = 0; ni < 4; ni++)
        acc[mi][ni] = __builtin_amdgcn_mfma_f32_16x16x32_bf16(af[mi], bfr[ni], acc[mi][ni], 0, 0, 0);
    __syncthreads();
  }

  const size_t m0 = (size_t)bm * 128 + wr * 64;
  const size_t n0 = (size_t)bn * 128 + wc * 64;
  #pragma unroll
  for (int mi = 0; mi < 4; mi++){
    #pragma unroll
    for (int ni = 0; ni < 4; ni++){
      size_t row = m0 + mi * 16 + kg * 4;
      size_t col = n0 + ni * 16 + r;
      float bvv = bias[col];
      #pragma unroll
      for (int rg = 0; rg < 4; rg++){
        float val = acc[mi][ni][rg] + bvv;
        if (OUT_BF16) ((unsigned short*)Cout)[(row + rg) * N + col] = f2bf(val);
        else          ((float*)Cout)[(row + rg) * N + col] = val;
      }
    }
  }
}

// ---------------------------------------------------------------- depthwise pool q (2x2 s2)
__global__ __launch_bounds__(256)
void pool_q_kernel(const unsigned short* __restrict__ qkv, const float* __restrict__ wq,
                   float* __restrict__ out)
{
  const int bid = blockIdx.x;            // 192*28
  const int bh = bid / 28, oy = bid % 28;
  const int b = bh / 12, h = bh % 12;
  __shared__ unsigned short in[112 * 66];
  const int t = threadIdx.x;
  for (int i = t; i < 112 * 32; i += 256){
    int slice = i >> 5, c2 = i & 31;
    int y = slice / 56, x = slice - y * 56;
    size_t ge = ((size_t)(b * 3136 + (2 * oy + y) * 56 + x)) * 2304 + (size_t)h * 64 + c2 * 2;
    *(unsigned int*)&in[slice * 66 + c2 * 2] = *(const unsigned int*)&qkv[ge];
  }
  __syncthreads();
  for (int o = t; o < 64 * 28; o += 256){
    int c = o / 28, ox = o - (o / 28) * 28;
    float w0 = wq[c * 4 + 0], w1 = wq[c * 4 + 1], w2 = wq[c * 4 + 2], w3 = wq[c * 4 + 3];
    int x0 = 2 * ox;
    float acc = bf2f(in[(x0    ) * 66 + c]) * w0 + bf2f(in[(x0 + 1     ) * 66 + c]) * w1
              + bf2f(in[(56 + x0) * 66 + c]) * w2 + bf2f(in[(56 + x0 + 1) * 66 + c]) * w3;
    out[(size_t)bh * 50176 + c * 784 + oy * 28 + ox] = acc;
  }
}

// ---------------------------------------------------------------- depthwise pool k (4x4 s4)
__global__ __launch_bounds__(256)
void pool_k_kernel(const unsigned short* __restrict__ qkv, const float* __restrict__ wk,
                   float* __restrict__ out)
{
  const int bid = blockIdx.x;            // 192*14
  const int bh = bid / 14, oy = bid % 14;
  const int b = bh / 12, h = bh % 12;
  __shared__ unsigned short in[224 * 66];
  const int t = threadIdx.x;
  for (int i = t; i < 224 * 32; i += 256){
    int slice = i >> 5, c2 = i & 31;
    int y = slice / 56, x = slice - y * 56;
    size_t ge = ((size_t)(b * 3136 + (4 * oy + y) * 56 + x)) * 2304 + 768 + (size_t)h * 64 + c2 * 2;
    *(unsigned int*)&in[slice * 66 + c2 * 2] = *(const unsigned int*)&qkv[ge];
  }
  __syncthreads();
  for (int o = t; o < 64 * 14; o += 256){
    int c = o / 14, ox = o % 14;
    float acc = 0.f;
    #pragma unroll
    for (int i2 = 0; i2 < 4; i2++)
      #pragma unroll
      for (int j2 = 0; j2 < 4; j2++)
        acc += bf2f(in[(i2 * 56 + 4 * ox + j2) * 66 + c]) * wk[c * 16 + i2 * 4 + j2];
    out[(size_t)bh * 12544 + c * 196 + oy * 14 + ox] = acc;
  }
}

// ---------------------------------------------------------------- full conv pool v via MFMA
__global__ __launch_bounds__(256)
void pool_v_kernel(const unsigned short* __restrict__ qkv, const unsigned short* __restrict__ wvb,
                   float* __restrict__ out)
{
  const int bid = blockIdx.x;            // 192*14
  const int bh = bid / 14, oy = bid % 14;
  const int b = bh / 12, h = bh % 12;
  __shared__ __align__(16) unsigned short in[224 * 72];
  const int t = threadIdx.x, lane = t & 63, w = t >> 6;

  for (int i = t; i < 224 * 32; i += 256){
    int slice = i >> 5, c2 = i & 31;
    int y = slice / 56, x = slice - y * 56;
    size_t ge = ((size_t)(b * 3136 + (4 * oy + y) * 56 + x)) * 2304 + 1536 + (size_t)h * 64 + c2 * 2;
    *(unsigned int*)&in[slice * 72 + c2 * 2] = *(const unsigned int*)&qkv[ge];
  }
  __syncthreads();

  const int r = lane & 15, kg = lane >> 4;
  const int ox = r;
  const int dv = w * 16 + r;
  f32x4 acc = (f32x4){0.f, 0.f, 0.f, 0.f};
  #pragma unroll 4
  for (int kt = 0; kt < 1024; kt += 32){
    int k0 = kt + kg * 8;
    int ij = k0 >> 6, c0 = k0 & 63;
    int i2 = ij >> 2, j2 = ij & 3;
    short8 af = {0, 0, 0, 0, 0, 0, 0, 0};
    if (ox < 14) af = *(const short8*)&in[(i2 * 56 + 4 * ox + j2) * 72 + c0];
    short8 bfr = *(const short8*)&wvb[(size_t)dv * 1024 + k0];
    acc = __builtin_amdgcn_mfma_f32_16x16x32_bf16(af, bfr, acc, 0, 0, 0);
  }
  #pragma unroll
  for (int rg = 0; rg < 4; rg++){
    int oxr = kg * 4 + rg;
    if (oxr < 14)
      out[(size_t)bh * 12544 + dv * 196 + oy * 14 + oxr] = acc[rg];
  }
}

// ---------------------------------------------------------------- MFMA fused attention
__global__ __launch_bounds__(256)
void attn2_kernel(const unsigned short* __restrict__ Qb, const unsigned short* __restrict__ Kb,
                  const unsigned short* __restrict__ Vtb, unsigned short* __restrict__ out)
{
  const int bid = blockIdx.x;            // 192*13
  const int bh = bid / 13, qt = bid % 13;
  const int b = bh / 12, h = bh % 12;
  __shared__ __align__(128) char K_lds[26624];   // 208x64 bf16, row-swizzled
  __shared__ __align__(128) char V_lds[26624];   // 64x208 bf16 (V^T), row-swizzled
  __shared__ __align__(128) char P_lds[26624];   // 64x208 bf16, row-swizzled
  const int t = threadIdx.x, lane = t & 63, w = t >> 6;
  const int r = lane & 15, kg = lane >> 4;
  const short8 z8 = {0, 0, 0, 0, 0, 0, 0, 0};

  const char* Kg = (const char*)Kb + (size_t)bh * 26624;
  const char* Vg = (const char*)Vtb + (size_t)bh * 26624;
  #pragma unroll
  for (int i = 0; i < 7; i++){
    int j = i * 256 + t;
    if (j < 1664) async16(Kg + j * 16, K_lds + j * 16);
  }
  #pragma unroll
  for (int i = 0; i < 7; i++){
    int j = i * 256 + t;
    if (j < 1664) async16(Vg + j * 16, V_lds + j * 16);
  }

  const size_t qrow = (size_t)bh * 784 + qt * 64 + w * 16 + r;
  short8 aq0 = *(const short8*)&Qb[qrow * 64 + kg * 8];
  short8 aq1 = *(const short8*)&Qb[qrow * 64 + 32 + kg * 8];

  __syncthreads();

  f32x4 s[13];
  #pragma unroll
  for (int nf = 0; nf < 13; nf++){
    int row = nf * 16 + r;
    short8 bk0 = *(const short8*)(K_lds + SWZ(row * 128 + kg * 16, row));
    short8 bk1 = *(const short8*)(K_lds + SWZ(row * 128 + 64 + kg * 16, row));
    f32x4 a = (f32x4){0.f, 0.f, 0.f, 0.f};
    a = __builtin_amdgcn_mfma_f32_16x16x32_bf16(aq0, bk0, a, 0, 0, 0);
    a = __builtin_amdgcn_mfma_f32_16x16x32_bf16(aq1, bk1, a, 0, 0, 0);
    s[nf] = a;
  }

  #pragma unroll
  for (int rg = 0; rg < 4; rg++) if (r >= 4) s[12][rg] = -1e30f;

  float inv[4];
  #pragma unroll
  for (int rg = 0; rg < 4; rg++){
    float m0 = s[0][rg];
    #pragma unroll
    for (int nf = 1; nf < 13; nf++) m0 = fmaxf(m0, s[nf][rg]);
    m0 = fmaxf(m0, __shfl_xor(m0, 1, 64));
    m0 = fmaxf(m0, __shfl_xor(m0, 2, 64));
    m0 = fmaxf(m0, __shfl_xor(m0, 4, 64));
    m0 = fmaxf(m0, __shfl_xor(m0, 8, 64));
    const int q = w * 16 + kg * 4 + rg;
    float sum = 0.f;
    #pragma unroll
    for (int nf = 0; nf < 13; nf++){
      float p = __expf(s[nf][rg] - m0);
      if (nf == 12 && r >= 4) p = 0.f;
      sum += p;
      *(unsigned short*)(P_lds + SWZ(q * 416 + (nf * 16 + r) * 2, q)) = f2bf(p);
    }
    sum += __shfl_xor(sum, 1, 64);
    sum += __shfl_xor(sum, 2, 64);
    sum += __shfl_xor(sum, 4, 64);
    sum += __shfl_xor(sum, 8, 64);
    inv[rg] = 1.f / sum;
  }

  f32x4 o[4];
  #pragma unroll
  for (int i = 0; i < 4; i++) o[i] = (f32x4){0.f, 0.f, 0.f, 0.f};
  const int qr = w * 16 + r;
  #pragma unroll
  for (int ks = 0; ks < 7; ks++){
    short8 ap = z8, bv0 = z8, bv1 = z8, bv2 = z8, bv3 = z8;
    if (ks < 6 || kg < 2){
      ap  = *(const short8*)(P_lds + SWZ(qr * 416 + ks * 64 + kg * 16, qr));
      bv0 = *(const short8*)(V_lds + SWZ((0 * 16 + r) * 416 + ks * 64 + kg * 16, (0 * 16 + r)));
      bv1 = *(const short8*)(V_lds + SWZ((1 * 16 + r) * 416 + ks * 64 + kg * 16, (1 * 16 + r)));
      bv2 = *(const short8*)(V_lds + SWZ((2 * 16 + r) * 416 + ks * 64 + kg * 16, (2 * 16 + r)));
      bv3 = *(const short8*)(V_lds + SWZ((3 * 16 + r) * 416 + ks * 64 + kg * 16, (3 * 16 + r)));
    }
    o[0] = __builtin_amdgcn_mfma_f32_16x16x32_bf16(ap, bv0, o[0], 0, 0, 0);
    o[1] = __builtin_amdgcn_mfma_f32_16x16x32_bf16(ap, bv1, o[1], 0, 0, 0);
    o[2] = __builtin_amdgcn_mfma_f32_16x16x32_bf16(ap, bv2, o[2], 0, 0, 0);
    o[3] = __builtin_amdgcn_mfma_f32_16x16x32_bf16(ap, bv3, o[3], 0, 0, 0);
  }

  #pragma unroll
  for (int rg = 0; rg < 4; rg++){
    int qg = qt * 64 + w * 16 + kg * 4 + rg;
    if (qg < 784){
      unsigned short* orow = out + ((size_t)b * 784 + qg) * 768 + h * 64;
      float sc = inv[rg];
      orow[ 0 + r] = f2bf(o[0][rg] * sc);
      orow[16 + r] = f2bf(o[1][rg] * sc);
      orow[32 + r] = f2bf(o[2][rg] * sc);
      orow[48 + r] = f2bf(o[3][rg] * sc);
    }
  }
}

// ---------------------------------------------------------------- launch
extern "C" void kernel_launch(void* const* d_in, const int* in_sizes, int n_in,
                              void* d_out, int out_size, void* d_ws, size_t ws_size,
                              hipStream_t stream)
{
  (void)in_sizes; (void)n_in; (void)out_size; (void)ws_size;
  const float* x      = (const float*)d_in[0];
  const float* norm_w = (const float*)d_in[3];
  const float* norm_b = (const float*)d_in[4];
  const float* qkv_w  = (const float*)d_in[5];
  const float* qkv_b  = (const float*)d_in[6];
  const float* pq_w   = (const float*)d_in[7];
  const float* pk_w   = (const float*)d_in[8];
  const float* pv_w   = (const float*)d_in[9];
  const float* nq_w   = (const float*)d_in[10];
  const float* nq_b   = (const float*)d_in[11];
  const float* nk_w   = (const float*)d_in[12];
  const float* nk_b   = (const float*)d_in[13];
  const float* nv_w   = (const float*)d_in[14];
  const float* nv_b   = (const float*)d_in[15];
  const float* proj_w = (const float*)d_in[16];
  const float* proj_b = (const float*)d_in[17];
  float* outp = (float*)d_out;

  char* ws = (char*)d_ws;
  size_t o = 0;
  unsigned short* wqkv16  = (unsigned short*)(ws + o); o += 3538944;
  unsigned short* wproj16 = (unsigned short*)(ws + o); o += 1179648;
  unsigned short* wv16    = (unsigned short*)(ws + o); o += 131072;
  char* xn_region         = (ws + o);                  o += 77070336;
  unsigned short* qkv     = (unsigned short*)(ws + o); o += 231211008;
  float*  qpool           = (float*)(ws + o);          o += 38535168;
  float*  kpool           = (float*)(ws + o);          o += 9633792;
  float*  vpool           = (float*)(ws + o);          o += 9633792;
  unsigned short* attno   = (unsigned short*)(ws + o); o += 19267584;

  unsigned short* xn  = (unsigned short*)xn_region;
  unsigned short* Qb  = (unsigned short*)xn_region;
  unsigned short* Kbt = (unsigned short*)(xn_region + 19275776);
  unsigned short* Vtb = (unsigned short*)(xn_region + 19275776 + 5111808);

  tobf16_kernel<<<(1769472 + 255) / 256, 256, 0, stream>>>(qkv_w, wqkv16, 1769472);
  tobf16_kernel<<<(589824 + 255) / 256, 256, 0, stream>>>(proj_w, wproj16, 589824);
  conv_wv_kernel<<<256, 256, 0, stream>>>(pv_w, wv16);

  ln768_kernel<<<12544, 256, 0, stream>>>(x, norm_w, norm_b, xn);

  gemm256<12><<<196 * 9, 512, 0, stream>>>(xn, wqkv16, qkv_b, qkv, 50176, 2304);

  pool_q_kernel<<<192 * 28, 256, 0, stream>>>(qkv, pq_w, qpool);
  pool_k_kernel<<<192 * 14, 256, 0, stream>>>(qkv, pk_w, kpool);
  pool_v_kernel<<<192 * 14, 256, 0, stream>>>(qkv, wv16, vpool);

  ln64q_kernel<<<150528 / 4, 256, 0, stream>>>(qpool, nq_w, nq_b, Qb);
  ln64k_kernel<<<37632 / 4, 256, 0, stream>>>(kpool, nk_w, nk_b, Kbt);
  vt_prep_kernel<<<192, 256, 0, stream>>>(vpool, nv_w, nv_b, Vtb);

  attn2_kernel<<<192 * 13, 256, 0, stream>>>(Qb, Kbt, Vtb, attno);

  gemm_bt<0><<<98 * 6, 256, 0, stream>>>(attno, wproj16, proj_b, outp, 12544, 768, 768);
}

// Round 4
// 423.180 us; speedup vs baseline: 2.5475x; 1.2200x over previous
//
#include <hip/hip_runtime.h>
#include <hip/hip_bf16.h>

using short8 = __attribute__((ext_vector_type(8))) short;
using f32x4  = __attribute__((ext_vector_type(4))) float;

#define DEVI __device__ __forceinline__
#define SWZ(byte, row) ((unsigned)(byte) ^ ((((unsigned)(row)) & 7u) << 4))

DEVI unsigned short f2bf(float f){
  unsigned int u = __float_as_uint(f);
  unsigned int r = (u + 0x7fffu + ((u >> 16) & 1u)) >> 16;
  return (unsigned short)r;
}
DEVI float bf2f(unsigned short u){ return __uint_as_float(((unsigned int)u) << 16); }

DEVI float wsum(float x){
  #pragma unroll
  for (int o = 32; o > 0; o >>= 1) x += __shfl_xor(x, o, 64);
  return x;
}

DEVI void async16(const void* g, void* l){
  __builtin_amdgcn_global_load_lds(
      (const __attribute__((address_space(1))) void*)g,
      (__attribute__((address_space(3))) void*)l,
      16, 0, 0);
}

// ---------------------------------------------------------------- weight casts
__global__ void tobf16_kernel(const float* __restrict__ in, unsigned short* __restrict__ out, int n){
  int i = blockIdx.x * 256 + threadIdx.x;
  if (i < n) out[i] = f2bf(in[i]);
}

// pool_v_w (dv, c, 4, 4) f32 -> wvb[dv][pos*64 + c] bf16, pos = window-permuted position
__global__ void conv_wv_kernel(const float* __restrict__ wv, unsigned short* __restrict__ wvb){
  int i = blockIdx.x * 256 + threadIdx.x;   // 64*64*16 = 65536
  if (i >= 65536) return;
  int dv = i >> 10, c = (i >> 4) & 63, ij = i & 15;
  int y = ij >> 2, x = ij & 3;
  int pos = ((((y >> 1) & 1) * 2 + ((x >> 1) & 1)) << 2) + (y & 1) * 2 + (x & 1);
  wvb[dv * 1024 + pos * 64 + c] = f2bf(wv[i]);
}

// ---------------------------------------------------------------- LN over 768, f32 in -> bf16 out
// dest rows PERMUTED: each 16 consecutive rows = one 4x4 pooling window
__global__ __launch_bounds__(256)
void ln768_kernel(const float* __restrict__ x, const float* __restrict__ w,
                  const float* __restrict__ b, unsigned short* __restrict__ out)
{
  const int row  = blockIdx.x * 4 + (threadIdx.x >> 6);
  const int lane = threadIdx.x & 63;
  const float* xr = x + (size_t)row * 768;
  f32x4 v[3];
  float s = 0.f, s2 = 0.f;
  #pragma unroll
  for (int kk = 0; kk < 3; kk++){
    v[kk] = *(const f32x4*)&xr[lane * 4 + kk * 256];
    #pragma unroll
    for (int e = 0; e < 4; e++){ s += v[kk][e]; s2 += v[kk][e] * v[kk][e]; }
  }
  s = wsum(s); s2 = wsum(s2);
  float mu  = s * (1.f / 768.f);
  float var = s2 * (1.f / 768.f) - mu * mu;
  float rs  = rsqrtf(var + 1e-6f);

  const int bimg = row / 3136, tkn = row % 3136;
  const int y = tkn / 56, xx = tkn % 56;
  const int win = (y >> 2) * 14 + (xx >> 2);
  const int pos = ((((y >> 1) & 1) * 2 + ((xx >> 1) & 1)) << 2) + (y & 1) * 2 + (xx & 1);
  unsigned short* orow = out + ((size_t)bimg * 3136 + win * 16 + pos) * 768;

  #pragma unroll
  for (int kk = 0; kk < 3; kk++){
    int c0 = lane * 4 + kk * 256;
    float y0 = (v[kk][0] - mu) * rs * w[c0 + 0] + b[c0 + 0];
    float y1 = (v[kk][1] - mu) * rs * w[c0 + 1] + b[c0 + 1];
    float y2 = (v[kk][2] - mu) * rs * w[c0 + 2] + b[c0 + 2];
    float y3 = (v[kk][3] - mu) * rs * w[c0 + 3] + b[c0 + 3];
    unsigned int lo = (unsigned int)f2bf(y0) | ((unsigned int)f2bf(y1) << 16);
    unsigned int hi = (unsigned int)f2bf(y2) | ((unsigned int)f2bf(y3) << 16);
    *(uint2*)&orow[c0] = make_uint2(lo, hi);
  }
}

// ---------------------------------------------------------------- LN64 -> bf16 Q (scale folded)
__global__ __launch_bounds__(256)
void ln64q_kernel(const float* __restrict__ in, const float* __restrict__ w,
                  const float* __restrict__ b, unsigned short* __restrict__ out)
{
  const size_t chunk = (size_t)blockIdx.x * 4 + (threadIdx.x >> 6);
  const int lane = threadIdx.x & 63;
  float xv = in[chunk * 64 + lane];
  float mu = wsum(xv) * (1.f / 64.f);
  float dl = xv - mu;
  float var = wsum(dl * dl) * (1.f / 64.f);
  float y = dl * rsqrtf(var + 1e-5f) * w[lane] + b[lane];
  out[chunk * 64 + lane] = f2bf(y * 0.125f);
}

// ---------------------------------------------------------------- LN64 -> swizzled Kb tile
__global__ __launch_bounds__(256)
void ln64k_kernel(const float* __restrict__ in, const float* __restrict__ w,
                  const float* __restrict__ b, unsigned short* __restrict__ Kb)
{
  const int chunk = blockIdx.x * 4 + (threadIdx.x >> 6);   // 192*196
  const int lane = threadIdx.x & 63;
  const int bh = chunk / 196, m = chunk % 196;
  float xv = in[(size_t)chunk * 64 + lane];
  float mu = wsum(xv) * (1.f / 64.f);
  float dl = xv - mu;
  float var = wsum(dl * dl) * (1.f / 64.f);
  float y = dl * rsqrtf(var + 1e-5f) * w[lane] + b[lane];
  char* og = (char*)Kb + (size_t)bh * 26624;
  *(unsigned short*)(og + SWZ(m * 128 + lane * 2, m)) = f2bf(y);
}

// ---------------------------------------------------------------- LN64 + transpose -> swizzled Vt tile
__global__ __launch_bounds__(256)
void vt_prep_kernel(const float* __restrict__ vpool, const float* __restrict__ w,
                    const float* __restrict__ b, unsigned short* __restrict__ Vtb)
{
  const int bh = blockIdx.x;                 // 192
  __shared__ float Ls[196 * 65];
  const float* vb = vpool + (size_t)bh * 12544;
  const int t = threadIdx.x, lane = t & 63, wv = t >> 6;
  for (int i = t; i < 12544; i += 256){
    int n = i >> 6, d = i & 63;
    Ls[n * 65 + d] = vb[i];
  }
  __syncthreads();
  for (int n = wv; n < 196; n += 4){
    float xv = Ls[n * 65 + lane];
    float mu = wsum(xv) * (1.f / 64.f);
    float dl = xv - mu;
    float var = wsum(dl * dl) * (1.f / 64.f);
    Ls[n * 65 + lane] = dl * rsqrtf(var + 1e-5f) * w[lane] + b[lane];
  }
  __syncthreads();
  char* og = (char*)Vtb + (size_t)bh * 26624;
  for (int j = t; j < 12544; j += 256){
    int d = j / 196, n = j % 196;
    *(unsigned short*)(og + SWZ(d * 416 + n * 2, d)) = f2bf(Ls[n * 65 + d]);
  }
  for (int j = t; j < 768; j += 256){        // zero pads n=196..207 (NaN-safe PV)
    int d = j / 12, n = 196 + j % 12;
    *(unsigned short*)(og + SWZ(d * 416 + n * 2, d)) = 0;
  }
}

// ---------------------------------------------------------------- 256x256 8-phase QKV GEMM, pool-fused epilogue
#define BAR() __builtin_amdgcn_s_barrier()
#define LGKM0() do{ asm volatile("s_waitcnt lgkmcnt(0)" ::: "memory"); __builtin_amdgcn_sched_barrier(0); }while(0)
#define VMW(N)  do{ asm volatile("s_waitcnt vmcnt(" #N ")" ::: "memory"); __builtin_amdgcn_sched_barrier(0); }while(0)

#define STAGE(GB, LOFF, KT, KS) do { \
  const unsigned short* gp_ = (GB) + (size_t)(KT) * 64 + (KS) * 32; \
  _Pragma("unroll") for (int l_ = 0; l_ < 2; ++l_){ \
    int i_ = l_ * 512 + tid; int row_ = i_ >> 2; int gch_ = (i_ & 3) ^ ((row_ >> 1) & 3); \
    async16(gp_ + (size_t)row_ * 768 + gch_ * 8, lds + (LOFF) + i_ * 16); \
  } } while(0)

#define LDA4(MH, KS) do { \
  _Pragma("unroll") for (int mm_ = 0; mm_ < 4; ++mm_){ \
    int row_ = wr * 128 + (MH) * 64 + mm_ * 16 + r; \
    Af[mm_] = *(const short8*)(lds + aoff + (KS) * 16384 + row_ * 64 + ((kg ^ ((row_ >> 1) & 3)) * 16)); \
  } } while(0)

#define LDB4(KS) do { \
  _Pragma("unroll") for (int nn_ = 0; nn_ < 4; ++nn_){ \
    int row_ = wc * 64 + nn_ * 16 + r; \
    Bf[nn_] = *(const short8*)(lds + boff + (KS) * 16384 + row_ * 64 + ((kg ^ ((row_ >> 1) & 3)) * 16)); \
  } } while(0)

#define MFMA16(MH) do { \
  __builtin_amdgcn_s_setprio(1); \
  _Pragma("unroll") for (int mm_ = 0; mm_ < 4; ++mm_) \
    _Pragma("unroll") for (int nn_ = 0; nn_ < 4; ++nn_) \
      acc[(MH) * 4 + mm_][nn_] = __builtin_amdgcn_mfma_f32_16x16x32_bf16(Af[mm_], Bf[nn_], acc[(MH) * 4 + mm_][nn_], 0, 0, 0); \
  __builtin_amdgcn_s_setprio(0); \
  } while(0)

__global__ __launch_bounds__(512, 2)
void gemm_qkv(const unsigned short* __restrict__ A, const unsigned short* __restrict__ W,
              const float* __restrict__ bias, const float* __restrict__ wq,
              const float* __restrict__ wk, float* __restrict__ qpool,
              float* __restrict__ kpool, unsigned short* __restrict__ vpart)
{
  constexpr int NT = 12;
  __shared__ __align__(128) char lds[131072];
  const int tid = threadIdx.x;
  const int lane = tid & 63, w = tid >> 6;
  const int r = lane & 15, kg = lane >> 4;
  const int wr = w >> 2, wc = w & 3;

  // bijective XCD swizzle (m204)
  const int nwg = gridDim.x;
  const int lq = nwg >> 3, lr = nwg & 7;
  const int xcd = blockIdx.x & 7;
  const int wg = (xcd < lr ? xcd * (lq + 1) : lr * (lq + 1) + (xcd - lr) * lq) + (blockIdx.x >> 3);
  const int bm = wg / 9, bn = wg % 9;

  const unsigned short* Ag = A + (size_t)bm * 256 * 768;
  const unsigned short* Wg = W + (size_t)bn * 256 * 768;

  f32x4 acc[8][4];
  #pragma unroll
  for (int i = 0; i < 8; i++)
    #pragma unroll
    for (int j = 0; j < 4; j++) acc[i][j] = (f32x4){0.f, 0.f, 0.f, 0.f};

  STAGE(Ag, 0, 0, 0);
  STAGE(Wg, 65536, 0, 0);
  STAGE(Ag, 16384, 0, 1);
  STAGE(Wg, 65536 + 16384, 0, 1);
  STAGE(Ag, 32768, 1, 0);
  STAGE(Wg, 65536 + 32768, 1, 0);
  VMW(4); BAR();

  for (int t = 0; t < NT; ++t){
    const int slot = t & 1;
    const int aoff = slot * 32768;
    const int boff = 65536 + slot * 32768;
    const int sn1 = ((t + 1) & 1) * 32768;
    const bool st1 = (t + 1 < NT), st2 = (t + 2 < NT);
    short8 Af[4], Bf[4];

    LDB4(0); LDA4(0, 0);
    if (st1) STAGE(Ag, sn1 + 16384, t + 1, 1);
    BAR(); LGKM0();
    MFMA16(0);
    BAR();
    LDA4(1, 0);
    if (st1) STAGE(Wg, 65536 + sn1 + 16384, t + 1, 1);
    BAR(); LGKM0();
    MFMA16(1);
    BAR();
    LDB4(1); LDA4(0, 1);
    if (st2) STAGE(Ag, aoff, t + 2, 0);
    BAR(); LGKM0();
    MFMA16(0);
    BAR();
    LDA4(1, 1);
    if (st2) STAGE(Wg, 65536 + aoff, t + 2, 0);
    BAR(); LGKM0();
    MFMA16(1);
    if (t < NT - 2) { VMW(4); }
    else if (t == NT - 2) { VMW(0); }
    BAR();
  }

  // ---- fused epilogue: bn 0-2 -> q-pool, 3-5 -> k-pool, 6-8 -> v matrix
  const int region = bn / 3;
  const int hh = (bn % 3) * 4 + wc;           // head 0..11 within region
  const size_t gn0 = (size_t)bn * 256 + wc * 64;

  if (region == 2){
    const size_t m0 = (size_t)bm * 256 + wr * 128;
    #pragma unroll
    for (int m = 0; m < 8; m++){
      const size_t row = m0 + m * 16 + kg * 4;
      #pragma unroll
      for (int n = 0; n < 4; n++){
        const size_t col = (size_t)(bn % 3) * 256 + wc * 64 + n * 16 + r;
        const float bv = bias[gn0 + n * 16 + r];
        #pragma unroll
        for (int rg = 0; rg < 4; rg++)
          vpart[(row + rg) * 768 + col] = f2bf(acc[m][n][rg] + bv);
      }
    }
  } else if (region == 0){
    #pragma unroll
    for (int n = 0; n < 4; n++){
      const int c = n * 16 + r;
      const float bv = bias[gn0 + n * 16 + r];
      const float w0 = wq[c * 4 + 0], w1 = wq[c * 4 + 1];
      const float w2 = wq[c * 4 + 2], w3 = wq[c * 4 + 3];
      #pragma unroll
      for (int m = 0; m < 8; m++){
        int gw = bm * 16 + wr * 8 + m;
        int bimg = gw / 196, wir = gw - bimg * 196;
        int wy = wir / 14, wx = wir - wy * 14;
        float pooled = (acc[m][n][0] + bv) * w0 + (acc[m][n][1] + bv) * w1
                     + (acc[m][n][2] + bv) * w2 + (acc[m][n][3] + bv) * w3;
        int qy = 2 * wy + (kg >> 1), qx = 2 * wx + (kg & 1);
        qpool[((size_t)(bimg * 12 + hh)) * 50176 + (size_t)c * 784 + qy * 28 + qx] = pooled;
      }
    }
  } else {
    #pragma unroll
    for (int n = 0; n < 4; n++){
      const int c = n * 16 + r;
      const float bv = bias[gn0 + n * 16 + r];
      float wkr[4];
      #pragma unroll
      for (int rg = 0; rg < 4; rg++){
        int widx = ((kg >> 1) * 2 + (rg >> 1)) * 4 + (kg & 1) * 2 + (rg & 1);
        wkr[rg] = wk[c * 16 + widx];
      }
      #pragma unroll
      for (int m = 0; m < 8; m++){
        int gw = bm * 16 + wr * 8 + m;
        int bimg = gw / 196, wir = gw - bimg * 196;
        float part = (acc[m][n][0] + bv) * wkr[0] + (acc[m][n][1] + bv) * wkr[1]
                   + (acc[m][n][2] + bv) * wkr[2] + (acc[m][n][3] + bv) * wkr[3];
        part += __shfl_xor(part, 16, 64);
        part += __shfl_xor(part, 32, 64);
        if (kg == 0)
          kpool[((size_t)(bimg * 12 + hh)) * 12544 + (size_t)c * 196 + wir] = part;
      }
    }
  }
}

// ---------------------------------------------------------------- 128x128 MFMA bf16 B^T GEMM (proj)
template <int OUT_BF16>
__global__ __launch_bounds__(256, 2)
void gemm_bt(const unsigned short* __restrict__ A, const unsigned short* __restrict__ W,
             const float* __restrict__ bias, void* __restrict__ Cout,
             int M, int N, int K)
{
  __shared__ short8 As8[512];
  __shared__ short8 Bs8[512];
  const int t = threadIdx.x;
  const int lane = t & 63;
  const int wv = t >> 6;
  const int wr = wv >> 1, wc = wv & 1;
  const int tiles_n = N >> 7;
  const int bm = blockIdx.x / tiles_n, bn = blockIdx.x % tiles_n;

  const unsigned short* Ag = A + (size_t)bm * 128 * K;
  const unsigned short* Wg = W + (size_t)bn * 128 * K;

  f32x4 acc[4][4];
  #pragma unroll
  for (int i = 0; i < 4; i++)
    #pragma unroll
    for (int j = 0; j < 4; j++) acc[i][j] = (f32x4){0.f, 0.f, 0.f, 0.f};

  const int r = lane & 15, kg = lane >> 4;

  for (int kt = 0; kt < K; kt += 32){
    #pragma unroll
    for (int j = 0; j < 2; j++){
      int c = j * 256 + t;
      int row = c >> 2, kc = c & 3;
      async16(Ag + (size_t)row * K + kt + kc * 8, &As8[c]);
      async16(Wg + (size_t)row * K + kt + kc * 8, &Bs8[c]);
    }
    __syncthreads();
    short8 af[4], bfr[4];
    #pragma unroll
    for (int mi = 0; mi < 4; mi++) af[mi] = As8[(wr * 64 + mi * 16 + r) * 4 + kg];
    #pragma unroll
    for (int ni = 0; ni < 4; ni++) bfr[ni] = Bs8[(wc * 64 + ni * 16 + r) * 4 + kg];
    #pragma unroll
    for (int mi = 0; mi < 4; mi++)
      #pragma unroll
      for (int ni = 0; ni < 4; ni++)
        acc[mi][ni] = __builtin_amdgcn_mfma_f32_16x16x32_bf16(af[mi], bfr[ni], acc[mi][ni], 0, 0, 0);
    __syncthreads();
  }

  const size_t m0 = (size_t)bm * 128 + wr * 64;
  const size_t n0 = (size_t)bn * 128 + wc * 64;
  #pragma unroll
  for (int mi = 0; mi < 4; mi++){
    #pragma unroll
    for (int ni = 0; ni < 4; ni++){
      size_t row = m0 + mi * 16 + kg * 4;
      size_t col = n0 + ni * 16 + r;
      float bvv = bias[col];
      #pragma unroll
      for (int rg = 0; rg < 4; rg++){
        float val = acc[mi][ni][rg] + bvv;
        if (OUT_BF16) ((unsigned short*)Cout)[(row + rg) * N + col] = f2bf(val);
        else          ((float*)Cout)[(row + rg) * N + col] = val;
      }
    }
  }
}

// ---------------------------------------------------------------- pool v: windows are contiguous 16-row blocks
// block = (bh, wy); A = 14 windows x (16 pos x 64 ch) from vpart, W = wvb[dv][1024]
__global__ __launch_bounds__(256)
void pool_v_kernel(const unsigned short* __restrict__ vpart, const unsigned short* __restrict__ wvb,
                   float* __restrict__ out)
{
  const int bid = blockIdx.x;            // 192*14
  const int bh = bid / 14, wy = bid % 14;
  const int b = bh / 12, h = bh % 12;
  __shared__ __align__(128) char Alds[14 * 2048];   // [win][128 chunks x 16B], chunk ^ (win&7)
  const int t = threadIdx.x, lane = t & 63, w = t >> 6;
  const int r = lane & 15, kg = lane >> 4;

  #pragma unroll
  for (int l = 0; l < 7; l++){
    int j = l * 256 + t;                 // 1792 chunks
    int win = j >> 7, s = j & 127;
    int gch = s ^ (win & 7);
    int p = gch >> 3, c8 = gch & 7;
    const unsigned short* src = vpart + ((size_t)(b * 3136 + (wy * 14 + win) * 16 + p)) * 768 + h * 64 + c8 * 8;
    async16(src, Alds + j * 16);
  }
  __syncthreads();

  f32x4 acc = (f32x4){0.f, 0.f, 0.f, 0.f};
  const int dv = w * 16 + r;
  #pragma unroll 4
  for (int kt = 0; kt < 1024; kt += 32){
    int ck = (kt >> 3) + kg;             // logical 16B chunk 0..127
    short8 af = *(const short8*)(Alds + r * 2048 + ((ck ^ (r & 7)) * 16));   // A row = window r
    short8 bfr = *(const short8*)&wvb[(size_t)dv * 1024 + kt + kg * 8];
    acc = __builtin_amdgcn_mfma_f32_16x16x32_bf16(af, bfr, acc, 0, 0, 0);
  }
  #pragma unroll
  for (int rg = 0; rg < 4; rg++){
    int wx = kg * 4 + rg;                // D row = window
    if (wx < 14)
      out[(size_t)bh * 12544 + (size_t)dv * 196 + wy * 14 + wx] = acc[rg];
  }
}

// ---------------------------------------------------------------- MFMA fused attention
__global__ __launch_bounds__(256)
void attn2_kernel(const unsigned short* __restrict__ Qb, const unsigned short* __restrict__ Kb,
                  const unsigned short* __restrict__ Vtb, unsigned short* __restrict__ out)
{
  const int bid = blockIdx.x;            // 192*13
  const int bh = bid / 13, qt = bid % 13;
  const int b = bh / 12, h = bh % 12;
  __shared__ __align__(128) char K_lds[26624];
  __shared__ __align__(128) char V_lds[26624];
  __shared__ __align__(128) char P_lds[26624];
  const int t = threadIdx.x, lane = t & 63, w = t >> 6;
  const int r = lane & 15, kg = lane >> 4;
  const short8 z8 = {0, 0, 0, 0, 0, 0, 0, 0};

  const char* Kg = (const char*)Kb + (size_t)bh * 26624;
  const char* Vg = (const char*)Vtb + (size_t)bh * 26624;
  #pragma unroll
  for (int i = 0; i < 7; i++){
    int j = i * 256 + t;
    if (j < 1664) async16(Kg + j * 16, K_lds + j * 16);
  }
  #pragma unroll
  for (int i = 0; i < 7; i++){
    int j = i * 256 + t;
    if (j < 1664) async16(Vg + j * 16, V_lds + j * 16);
  }

  const size_t qrow = (size_t)bh * 784 + qt * 64 + w * 16 + r;
  short8 aq0 = *(const short8*)&Qb[qrow * 64 + kg * 8];
  short8 aq1 = *(const short8*)&Qb[qrow * 64 + 32 + kg * 8];

  __syncthreads();

  f32x4 s[13];
  #pragma unroll
  for (int nf = 0; nf < 13; nf++){
    int row = nf * 16 + r;
    short8 bk0 = *(const short8*)(K_lds + SWZ(row * 128 + kg * 16, row));
    short8 bk1 = *(const short8*)(K_lds + SWZ(row * 128 + 64 + kg * 16, row));
    f32x4 a = (f32x4){0.f, 0.f, 0.f, 0.f};
    a = __builtin_amdgcn_mfma_f32_16x16x32_bf16(aq0, bk0, a, 0, 0, 0);
    a = __builtin_amdgcn_mfma_f32_16x16x32_bf16(aq1, bk1, a, 0, 0, 0);
    s[nf] = a;
  }

  #pragma unroll
  for (int rg = 0; rg < 4; rg++) if (r >= 4) s[12][rg] = -1e30f;

  float inv[4];
  #pragma unroll
  for (int rg = 0; rg < 4; rg++){
    float m0 = s[0][rg];
    #pragma unroll
    for (int nf = 1; nf < 13; nf++) m0 = fmaxf(m0, s[nf][rg]);
    m0 = fmaxf(m0, __shfl_xor(m0, 1, 64));
    m0 = fmaxf(m0, __shfl_xor(m0, 2, 64));
    m0 = fmaxf(m0, __shfl_xor(m0, 4, 64));
    m0 = fmaxf(m0, __shfl_xor(m0, 8, 64));
    const int q = w * 16 + kg * 4 + rg;
    float sum = 0.f;
    #pragma unroll
    for (int nf = 0; nf < 13; nf++){
      float p = __expf(s[nf][rg] - m0);
      if (nf == 12 && r >= 4) p = 0.f;
      sum += p;
      *(unsigned short*)(P_lds + SWZ(q * 416 + (nf * 16 + r) * 2, q)) = f2bf(p);
    }
    sum += __shfl_xor(sum, 1, 64);
    sum += __shfl_xor(sum, 2, 64);
    sum += __shfl_xor(sum, 4, 64);
    sum += __shfl_xor(sum, 8, 64);
    inv[rg] = 1.f / sum;
  }

  f32x4 o[4];
  #pragma unroll
  for (int i = 0; i < 4; i++) o[i] = (f32x4){0.f, 0.f, 0.f, 0.f};
  const int qr = w * 16 + r;
  #pragma unroll
  for (int ks = 0; ks < 7; ks++){
    short8 ap = z8, bv0 = z8, bv1 = z8, bv2 = z8, bv3 = z8;
    if (ks < 6 || kg < 2){
      ap  = *(const short8*)(P_lds + SWZ(qr * 416 + ks * 64 + kg * 16, qr));
      bv0 = *(const short8*)(V_lds + SWZ((0 * 16 + r) * 416 + ks * 64 + kg * 16, (0 * 16 + r)));
      bv1 = *(const short8*)(V_lds + SWZ((1 * 16 + r) * 416 + ks * 64 + kg * 16, (1 * 16 + r)));
      bv2 = *(const short8*)(V_lds + SWZ((2 * 16 + r) * 416 + ks * 64 + kg * 16, (2 * 16 + r)));
      bv3 = *(const short8*)(V_lds + SWZ((3 * 16 + r) * 416 + ks * 64 + kg * 16, (3 * 16 + r)));
    }
    o[0] = __builtin_amdgcn_mfma_f32_16x16x32_bf16(ap, bv0, o[0], 0, 0, 0);
    o[1] = __builtin_amdgcn_mfma_f32_16x16x32_bf16(ap, bv1, o[1], 0, 0, 0);
    o[2] = __builtin_amdgcn_mfma_f32_16x16x32_bf16(ap, bv2, o[2], 0, 0, 0);
    o[3] = __builtin_amdgcn_mfma_f32_16x16x32_bf16(ap, bv3, o[3], 0, 0, 0);
  }

  #pragma unroll
  for (int rg = 0; rg < 4; rg++){
    int qg = qt * 64 + w * 16 + kg * 4 + rg;
    if (qg < 784){
      unsigned short* orow = out + ((size_t)b * 784 + qg) * 768 + h * 64;
      float sc = inv[rg];
      orow[ 0 + r] = f2bf(o[0][rg] * sc);
      orow[16 + r] = f2bf(o[1][rg] * sc);
      orow[32 + r] = f2bf(o[2][rg] * sc);
      orow[48 + r] = f2bf(o[3][rg] * sc);
    }
  }
}

// ---------------------------------------------------------------- launch
extern "C" void kernel_launch(void* const* d_in, const int* in_sizes, int n_in,
                              void* d_out, int out_size, void* d_ws, size_t ws_size,
                              hipStream_t stream)
{
  (void)in_sizes; (void)n_in; (void)out_size; (void)ws_size;
  const float* x      = (const float*)d_in[0];
  const float* norm_w = (const float*)d_in[3];
  const float* norm_b = (const float*)d_in[4];
  const float* qkv_w  = (const float*)d_in[5];
  const float* qkv_b  = (const float*)d_in[6];
  const float* pq_w   = (const float*)d_in[7];
  const float* pk_w   = (const float*)d_in[8];
  const float* pv_w   = (const float*)d_in[9];
  const float* nq_w   = (const float*)d_in[10];
  const float* nq_b   = (const float*)d_in[11];
  const float* nk_w   = (const float*)d_in[12];
  const float* nk_b   = (const float*)d_in[13];
  const float* nv_w   = (const float*)d_in[14];
  const float* nv_b   = (const float*)d_in[15];
  const float* proj_w = (const float*)d_in[16];
  const float* proj_b = (const float*)d_in[17];
  float* outp = (float*)d_out;

  char* ws = (char*)d_ws;
  size_t o = 0;
  unsigned short* wqkv16  = (unsigned short*)(ws + o); o += 3538944;    // 2304x768 bf16
  unsigned short* wproj16 = (unsigned short*)(ws + o); o += 1179648;    // 768x768 bf16
  unsigned short* wv16    = (unsigned short*)(ws + o); o += 131072;     // 64x1024 bf16
  char* xn_region         = (ws + o);                  o += 77070336;   // xn; later Qb/Kb/Vtb
  unsigned short* vpart   = (unsigned short*)(ws + o); o += 77070336;   // 50176x768 bf16
  float*  qpool           = (float*)(ws + o);          o += 38535168;   // 192x50176 f32
  float*  kpool           = (float*)(ws + o);          o += 9633792;    // 192x12544 f32
  float*  vpool           = (float*)(ws + o);          o += 9633792;
  unsigned short* attno   = (unsigned short*)(ws + o); o += 19267584;   // 12544x768 bf16

  unsigned short* xn  = (unsigned short*)xn_region;
  unsigned short* Qb  = (unsigned short*)xn_region;
  unsigned short* Kbt = (unsigned short*)(xn_region + 19275776);
  unsigned short* Vtb = (unsigned short*)(xn_region + 19275776 + 5111808);

  tobf16_kernel<<<(1769472 + 255) / 256, 256, 0, stream>>>(qkv_w, wqkv16, 1769472);
  tobf16_kernel<<<(589824 + 255) / 256, 256, 0, stream>>>(proj_w, wproj16, 589824);
  conv_wv_kernel<<<256, 256, 0, stream>>>(pv_w, wv16);

  ln768_kernel<<<12544, 256, 0, stream>>>(x, norm_w, norm_b, xn);

  gemm_qkv<<<196 * 9, 512, 0, stream>>>(xn, wqkv16, qkv_b, pq_w, pk_w, qpool, kpool, vpart);

  pool_v_kernel<<<192 * 14, 256, 0, stream>>>(vpart, wv16, vpool);

  ln64q_kernel<<<150528 / 4, 256, 0, stream>>>(qpool, nq_w, nq_b, Qb);
  ln64k_kernel<<<37632 / 4, 256, 0, stream>>>(kpool, nk_w, nk_b, Kbt);
  vt_prep_kernel<<<192, 256, 0, stream>>>(vpool, nv_w, nv_b, Vtb);

  attn2_kernel<<<192 * 13, 256, 0, stream>>>(Qb, Kbt, Vtb, attno);

  gemm_bt<0><<<98 * 6, 256, 0, stream>>>(attno, wproj16, proj_b, outp, 12544, 768, 768);
}

// Round 5
// 401.331 us; speedup vs baseline: 2.6862x; 1.0544x over previous
//
#include <hip/hip_runtime.h>
#include <hip/hip_bf16.h>

using short8 = __attribute__((ext_vector_type(8))) short;
using f32x4  = __attribute__((ext_vector_type(4))) float;

#define DEVI __device__ __forceinline__
#define SWZ(byte, row) ((unsigned)(byte) ^ ((((unsigned)(row)) & 7u) << 4))

DEVI unsigned short f2bf(float f){
  unsigned int u = __float_as_uint(f);
  unsigned int r = (u + 0x7fffu + ((u >> 16) & 1u)) >> 16;
  return (unsigned short)r;
}
DEVI float bf2f(unsigned short u){ return __uint_as_float(((unsigned int)u) << 16); }

DEVI float wsum(float x){
  #pragma unroll
  for (int o = 32; o > 0; o >>= 1) x += __shfl_xor(x, o, 64);
  return x;
}

DEVI void async16(const void* g, void* l){
  __builtin_amdgcn_global_load_lds(
      (const __attribute__((address_space(1))) void*)g,
      (__attribute__((address_space(3))) void*)l,
      16, 0, 0);
}

// ---------------------------------------------------------------- weight casts
__global__ void tobf16_kernel(const float* __restrict__ in, unsigned short* __restrict__ out, int n){
  int i = blockIdx.x * 256 + threadIdx.x;
  if (i < n) out[i] = f2bf(in[i]);
}

// pool_v_w (dv, c, 4, 4) f32 -> wvb[dv][pos*64 + c] bf16, pos = window-permuted position
__global__ void conv_wv_kernel(const float* __restrict__ wv, unsigned short* __restrict__ wvb){
  int i = blockIdx.x * 256 + threadIdx.x;   // 64*64*16 = 65536
  if (i >= 65536) return;
  int dv = i >> 10, c = (i >> 4) & 63, ij = i & 15;
  int y = ij >> 2, x = ij & 3;
  int pos = ((((y >> 1) & 1) * 2 + ((x >> 1) & 1)) << 2) + (y & 1) * 2 + (x & 1);
  wvb[dv * 1024 + pos * 64 + c] = f2bf(wv[i]);
}

// ---------------------------------------------------------------- LN over 768, f32 in -> bf16 out
// dest rows PERMUTED: each 16 consecutive rows = one 4x4 pooling window
__global__ __launch_bounds__(256)
void ln768_kernel(const float* __restrict__ x, const float* __restrict__ w,
                  const float* __restrict__ b, unsigned short* __restrict__ out)
{
  const int row  = blockIdx.x * 4 + (threadIdx.x >> 6);
  const int lane = threadIdx.x & 63;
  const float* xr = x + (size_t)row * 768;
  f32x4 v[3];
  float s = 0.f, s2 = 0.f;
  #pragma unroll
  for (int kk = 0; kk < 3; kk++){
    v[kk] = *(const f32x4*)&xr[lane * 4 + kk * 256];
    #pragma unroll
    for (int e = 0; e < 4; e++){ s += v[kk][e]; s2 += v[kk][e] * v[kk][e]; }
  }
  s = wsum(s); s2 = wsum(s2);
  float mu  = s * (1.f / 768.f);
  float var = s2 * (1.f / 768.f) - mu * mu;
  float rs  = rsqrtf(var + 1e-6f);

  const int bimg = row / 3136, tkn = row % 3136;
  const int y = tkn / 56, xx = tkn % 56;
  const int win = (y >> 2) * 14 + (xx >> 2);
  const int pos = ((((y >> 1) & 1) * 2 + ((xx >> 1) & 1)) << 2) + (y & 1) * 2 + (xx & 1);
  unsigned short* orow = out + ((size_t)bimg * 3136 + win * 16 + pos) * 768;

  #pragma unroll
  for (int kk = 0; kk < 3; kk++){
    int c0 = lane * 4 + kk * 256;
    float y0 = (v[kk][0] - mu) * rs * w[c0 + 0] + b[c0 + 0];
    float y1 = (v[kk][1] - mu) * rs * w[c0 + 1] + b[c0 + 1];
    float y2 = (v[kk][2] - mu) * rs * w[c0 + 2] + b[c0 + 2];
    float y3 = (v[kk][3] - mu) * rs * w[c0 + 3] + b[c0 + 3];
    unsigned int lo = (unsigned int)f2bf(y0) | ((unsigned int)f2bf(y1) << 16);
    unsigned int hi = (unsigned int)f2bf(y2) | ((unsigned int)f2bf(y3) << 16);
    *(uint2*)&orow[c0] = make_uint2(lo, hi);
  }
}

// ---------------------------------------------------------------- LN64 -> swizzled Kb tile
__global__ __launch_bounds__(256)
void ln64k_kernel(const float* __restrict__ in, const float* __restrict__ w,
                  const float* __restrict__ b, unsigned short* __restrict__ Kb)
{
  const int chunk = blockIdx.x * 4 + (threadIdx.x >> 6);   // 192*196
  const int lane = threadIdx.x & 63;
  const int bh = chunk / 196, m = chunk % 196;
  float xv = in[(size_t)chunk * 64 + lane];
  float mu = wsum(xv) * (1.f / 64.f);
  float dl = xv - mu;
  float var = wsum(dl * dl) * (1.f / 64.f);
  float y = dl * rsqrtf(var + 1e-5f) * w[lane] + b[lane];
  char* og = (char*)Kb + (size_t)bh * 26624;
  *(unsigned short*)(og + SWZ(m * 128 + lane * 2, m)) = f2bf(y);
}

// ---------------------------------------------------------------- LN64 + transpose -> swizzled Vt tile
__global__ __launch_bounds__(256)
void vt_prep_kernel(const float* __restrict__ vpool, const float* __restrict__ w,
                    const float* __restrict__ b, unsigned short* __restrict__ Vtb)
{
  const int bh = blockIdx.x;                 // 192
  __shared__ float Ls[196 * 65];
  const float* vb = vpool + (size_t)bh * 12544;
  const int t = threadIdx.x, lane = t & 63, wv = t >> 6;
  for (int i = t; i < 12544; i += 256){
    int n = i >> 6, d = i & 63;
    Ls[n * 65 + d] = vb[i];
  }
  __syncthreads();
  for (int n = wv; n < 196; n += 4){
    float xv = Ls[n * 65 + lane];
    float mu = wsum(xv) * (1.f / 64.f);
    float dl = xv - mu;
    float var = wsum(dl * dl) * (1.f / 64.f);
    Ls[n * 65 + lane] = dl * rsqrtf(var + 1e-5f) * w[lane] + b[lane];
  }
  __syncthreads();
  char* og = (char*)Vtb + (size_t)bh * 26624;
  for (int j = t; j < 12544; j += 256){
    int d = j / 196, n = j % 196;
    *(unsigned short*)(og + SWZ(d * 416 + n * 2, d)) = f2bf(Ls[n * 65 + d]);
  }
  for (int j = t; j < 768; j += 256){        // zero pads n=196..207 (NaN-safe PV)
    int d = j / 12, n = 196 + j % 12;
    *(unsigned short*)(og + SWZ(d * 416 + n * 2, d)) = 0;
  }
}

// ---------------------------------------------------------------- 256x256 8-phase QKV GEMM, pool-fused epilogue
#define BAR() __builtin_amdgcn_s_barrier()
#define LGKM0() do{ asm volatile("s_waitcnt lgkmcnt(0)" ::: "memory"); __builtin_amdgcn_sched_barrier(0); }while(0)
#define VMW(N)  do{ asm volatile("s_waitcnt vmcnt(" #N ")" ::: "memory"); __builtin_amdgcn_sched_barrier(0); }while(0)

#define STAGE(GB, LOFF, KT, KS) do { \
  const unsigned short* gp_ = (GB) + (size_t)(KT) * 64 + (KS) * 32; \
  _Pragma("unroll") for (int l_ = 0; l_ < 2; ++l_){ \
    int i_ = l_ * 512 + tid; int row_ = i_ >> 2; int gch_ = (i_ & 3) ^ ((row_ >> 1) & 3); \
    async16(gp_ + (size_t)row_ * 768 + gch_ * 8, lds + (LOFF) + i_ * 16); \
  } } while(0)

#define LDA4(MH, KS) do { \
  _Pragma("unroll") for (int mm_ = 0; mm_ < 4; ++mm_){ \
    int row_ = wr * 128 + (MH) * 64 + mm_ * 16 + r; \
    Af[mm_] = *(const short8*)(lds + aoff + (KS) * 16384 + row_ * 64 + ((kg ^ ((row_ >> 1) & 3)) * 16)); \
  } } while(0)

#define LDB4(KS) do { \
  _Pragma("unroll") for (int nn_ = 0; nn_ < 4; ++nn_){ \
    int row_ = wc * 64 + nn_ * 16 + r; \
    Bf[nn_] = *(const short8*)(lds + boff + (KS) * 16384 + row_ * 64 + ((kg ^ ((row_ >> 1) & 3)) * 16)); \
  } } while(0)

#define MFMA16(MH) do { \
  __builtin_amdgcn_s_setprio(1); \
  _Pragma("unroll") for (int mm_ = 0; mm_ < 4; ++mm_) \
    _Pragma("unroll") for (int nn_ = 0; nn_ < 4; ++nn_) \
      acc[(MH) * 4 + mm_][nn_] = __builtin_amdgcn_mfma_f32_16x16x32_bf16(Af[mm_], Bf[nn_], acc[(MH) * 4 + mm_][nn_], 0, 0, 0); \
  __builtin_amdgcn_s_setprio(0); \
  } while(0)

__global__ __launch_bounds__(512, 2)
void gemm_qkv(const unsigned short* __restrict__ A, const unsigned short* __restrict__ W,
              const float* __restrict__ bias, const float* __restrict__ wq,
              const float* __restrict__ wk, const unsigned short* __restrict__ wvb,
              float* __restrict__ qpool, float* __restrict__ kpool,
              float* __restrict__ vpool)
{
  constexpr int NT = 12;
  __shared__ __align__(128) char lds[131072];
  const int tid = threadIdx.x;
  const int lane = tid & 63, w = tid >> 6;
  const int r = lane & 15, kg = lane >> 4;
  const int wr = w >> 2, wc = w & 3;

  // bijective XCD swizzle (m204)
  const int nwg = gridDim.x;
  const int lq = nwg >> 3, lr = nwg & 7;
  const int xcd = blockIdx.x & 7;
  const int wg = (xcd < lr ? xcd * (lq + 1) : lr * (lq + 1) + (xcd - lr) * lq) + (blockIdx.x >> 3);
  const int bm = wg / 9, bn = wg % 9;

  const unsigned short* Ag = A + (size_t)bm * 256 * 768;
  const unsigned short* Wg = W + (size_t)bn * 256 * 768;

  f32x4 acc[8][4];
  #pragma unroll
  for (int i = 0; i < 8; i++)
    #pragma unroll
    for (int j = 0; j < 4; j++) acc[i][j] = (f32x4){0.f, 0.f, 0.f, 0.f};

  STAGE(Ag, 0, 0, 0);
  STAGE(Wg, 65536, 0, 0);
  STAGE(Ag, 16384, 0, 1);
  STAGE(Wg, 65536 + 16384, 0, 1);
  STAGE(Ag, 32768, 1, 0);
  STAGE(Wg, 65536 + 32768, 1, 0);
  VMW(4); BAR();

  for (int t = 0; t < NT; ++t){
    const int slot = t & 1;
    const int aoff = slot * 32768;
    const int boff = 65536 + slot * 32768;
    const int sn1 = ((t + 1) & 1) * 32768;
    const bool st1 = (t + 1 < NT), st2 = (t + 2 < NT);
    short8 Af[4], Bf[4];

    LDB4(0); LDA4(0, 0);
    if (st1) STAGE(Ag, sn1 + 16384, t + 1, 1);
    BAR(); LGKM0();
    MFMA16(0);
    BAR();
    LDA4(1, 0);
    if (st1) STAGE(Wg, 65536 + sn1 + 16384, t + 1, 1);
    BAR(); LGKM0();
    MFMA16(1);
    BAR();
    LDB4(1); LDA4(0, 1);
    if (st2) STAGE(Ag, aoff, t + 2, 0);
    BAR(); LGKM0();
    MFMA16(0);
    BAR();
    LDA4(1, 1);
    if (st2) STAGE(Wg, 65536 + aoff, t + 2, 0);
    BAR(); LGKM0();
    MFMA16(1);
    if (t < NT - 2) { VMW(4); }
    else if (t == NT - 2) { VMW(0); }
    BAR();
  }

  // ---- fused epilogue: bn 0-2 -> q-pool, 3-5 -> k-pool, 6-8 -> v-pool (full conv via LDS+MFMA)
  const int region = bn / 3;
  const int hh = (bn % 3) * 4 + wc;           // head 0..11 within region
  const size_t gn0 = (size_t)bn * 256 + wc * 64;

  if (region == 2){
    // 1) acc -> Av LDS: [hh 4][win 16][128 chunks x16B], chunk ^= (win&7)
    #pragma unroll
    for (int m = 0; m < 8; m++){
      const int win = wr * 8 + m;
      #pragma unroll
      for (int n = 0; n < 4; n++){
        const int c = n * 16 + r;
        const float bv = bias[gn0 + n * 16 + r];
        #pragma unroll
        for (int rg = 0; rg < 4; rg++){
          const int pos = kg * 4 + rg;
          const int chs = (pos * 8 + (c >> 3)) ^ (win & 7);
          *(unsigned short*)(lds + wc * 32768 + win * 2048 + chs * 16 + (c & 7) * 2)
              = f2bf(acc[m][n][rg] + bv);
        }
      }
    }
    BAR();
    // 2) pool GEMM: out[win 16][dv 64] = Av[win][k1024] x wvb[dv][k1024], per head
    const int hh2 = (bn % 3) * 4 + (w & 3);
    const char* Av = lds + (w & 3) * 32768;
    #pragma unroll
    for (int dg = 0; dg < 2; dg++){
      const int dvg = (w >> 2) * 2 + dg;
      f32x4 a2 = (f32x4){0.f, 0.f, 0.f, 0.f};
      #pragma unroll 4
      for (int kt = 0; kt < 1024; kt += 32){
        int ck = (kt >> 3) + kg;
        short8 af = *(const short8*)(Av + r * 2048 + ((ck ^ (r & 7)) * 16));
        short8 bfr = *(const short8*)&wvb[(size_t)(dvg * 16 + r) * 1024 + kt + kg * 8];
        a2 = __builtin_amdgcn_mfma_f32_16x16x32_bf16(af, bfr, a2, 0, 0, 0);
      }
      #pragma unroll
      for (int rg = 0; rg < 4; rg++){
        int gw = bm * 16 + kg * 4 + rg;
        int bimg = gw / 196, wir = gw - bimg * 196;
        vpool[((size_t)(bimg * 12 + hh2)) * 12544 + (size_t)(dvg * 16 + r) * 196 + wir] = a2[rg];
      }
    }
  } else if (region == 0){
    #pragma unroll
    for (int n = 0; n < 4; n++){
      const int c = n * 16 + r;
      const float bv = bias[gn0 + n * 16 + r];
      const float w0 = wq[c * 4 + 0], w1 = wq[c * 4 + 1];
      const float w2 = wq[c * 4 + 2], w3 = wq[c * 4 + 3];
      #pragma unroll
      for (int m = 0; m < 8; m++){
        int gw = bm * 16 + wr * 8 + m;
        int bimg = gw / 196, wir = gw - bimg * 196;
        int wy = wir / 14, wx = wir - wy * 14;
        float pooled = (acc[m][n][0] + bv) * w0 + (acc[m][n][1] + bv) * w1
                     + (acc[m][n][2] + bv) * w2 + (acc[m][n][3] + bv) * w3;
        int qy = 2 * wy + (kg >> 1), qx = 2 * wx + (kg & 1);
        qpool[((size_t)(bimg * 12 + hh)) * 50176 + (size_t)c * 784 + qy * 28 + qx] = pooled;
      }
    }
  } else {
    #pragma unroll
    for (int n = 0; n < 4; n++){
      const int c = n * 16 + r;
      const float bv = bias[gn0 + n * 16 + r];
      float wkr[4];
      #pragma unroll
      for (int rg = 0; rg < 4; rg++){
        int widx = ((kg >> 1) * 2 + (rg >> 1)) * 4 + (kg & 1) * 2 + (rg & 1);
        wkr[rg] = wk[c * 16 + widx];
      }
      #pragma unroll
      for (int m = 0; m < 8; m++){
        int gw = bm * 16 + wr * 8 + m;
        int bimg = gw / 196, wir = gw - bimg * 196;
        float part = (acc[m][n][0] + bv) * wkr[0] + (acc[m][n][1] + bv) * wkr[1]
                   + (acc[m][n][2] + bv) * wkr[2] + (acc[m][n][3] + bv) * wkr[3];
        part += __shfl_xor(part, 16, 64);
        part += __shfl_xor(part, 32, 64);
        if (kg == 0)
          kpool[((size_t)(bimg * 12 + hh)) * 12544 + (size_t)c * 196 + wir] = part;
      }
    }
  }
}

// ---------------------------------------------------------------- 128x128 MFMA bf16 B^T GEMM (proj)
template <int OUT_BF16>
__global__ __launch_bounds__(256, 2)
void gemm_bt(const unsigned short* __restrict__ A, const unsigned short* __restrict__ W,
             const float* __restrict__ bias, void* __restrict__ Cout,
             int M, int N, int K)
{
  __shared__ short8 As8[512];
  __shared__ short8 Bs8[512];
  const int t = threadIdx.x;
  const int lane = t & 63;
  const int wv = t >> 6;
  const int wr = wv >> 1, wc = wv & 1;
  const int tiles_n = N >> 7;
  const int bm = blockIdx.x / tiles_n, bn = blockIdx.x % tiles_n;

  const unsigned short* Ag = A + (size_t)bm * 128 * K;
  const unsigned short* Wg = W + (size_t)bn * 128 * K;

  f32x4 acc[4][4];
  #pragma unroll
  for (int i = 0; i < 4; i++)
    #pragma unroll
    for (int j = 0; j < 4; j++) acc[i][j] = (f32x4){0.f, 0.f, 0.f, 0.f};

  const int r = lane & 15, kg = lane >> 4;

  for (int kt = 0; kt < K; kt += 32){
    #pragma unroll
    for (int j = 0; j < 2; j++){
      int c = j * 256 + t;
      int row = c >> 2, kc = c & 3;
      async16(Ag + (size_t)row * K + kt + kc * 8, &As8[c]);
      async16(Wg + (size_t)row * K + kt + kc * 8, &Bs8[c]);
    }
    __syncthreads();
    short8 af[4], bfr[4];
    #pragma unroll
    for (int mi = 0; mi < 4; mi++) af[mi] = As8[(wr * 64 + mi * 16 + r) * 4 + kg];
    #pragma unroll
    for (int ni = 0; ni < 4; ni++) bfr[ni] = Bs8[(wc * 64 + ni * 16 + r) * 4 + kg];
    #pragma unroll
    for (int mi = 0; mi < 4; mi++)
      #pragma unroll
      for (int ni = 0; ni < 4; ni++)
        acc[mi][ni] = __builtin_amdgcn_mfma_f32_16x16x32_bf16(af[mi], bfr[ni], acc[mi][ni], 0, 0, 0);
    __syncthreads();
  }

  const size_t m0 = (size_t)bm * 128 + wr * 64;
  const size_t n0 = (size_t)bn * 128 + wc * 64;
  #pragma unroll
  for (int mi = 0; mi < 4; mi++){
    #pragma unroll
    for (int ni = 0; ni < 4; ni++){
      size_t row = m0 + mi * 16 + kg * 4;
      size_t col = n0 + ni * 16 + r;
      float bvv = bias[col];
      #pragma unroll
      for (int rg = 0; rg < 4; rg++){
        float val = acc[mi][ni][rg] + bvv;
        if (OUT_BF16) ((unsigned short*)Cout)[(row + rg) * N + col] = f2bf(val);
        else          ((float*)Cout)[(row + rg) * N + col] = val;
      }
    }
  }
}

// ---------------------------------------------------------------- MFMA fused attention (LN_q fused)
__global__ __launch_bounds__(256)
void attn2_kernel(const float* __restrict__ qpool, const float* __restrict__ nqw,
                  const float* __restrict__ nqb, const unsigned short* __restrict__ Kb,
                  const unsigned short* __restrict__ Vtb, unsigned short* __restrict__ out)
{
  const int bid = blockIdx.x;            // 192*13
  const int bh = bid / 13, qt = bid % 13;
  const int b = bh / 12, h = bh % 12;
  __shared__ __align__(128) char K_lds[26624];
  __shared__ __align__(128) char V_lds[26624];
  __shared__ __align__(128) char P_lds[26624];
  const int t = threadIdx.x, lane = t & 63, w = t >> 6;
  const int r = lane & 15, kg = lane >> 4;
  const short8 z8 = {0, 0, 0, 0, 0, 0, 0, 0};

  const char* Kg = (const char*)Kb + (size_t)bh * 26624;
  const char* Vg = (const char*)Vtb + (size_t)bh * 26624;
  #pragma unroll
  for (int i = 0; i < 7; i++){
    int j = i * 256 + t;
    if (j < 1664) async16(Kg + j * 16, K_lds + j * 16);
  }
  #pragma unroll
  for (int i = 0; i < 7; i++){
    int j = i * 256 + t;
    if (j < 1664) async16(Vg + j * 16, V_lds + j * 16);
  }

  // ---- Q row in fragment layout + fused LN (row's 64 elems live in kg=0..3 lanes at fixed r)
  const float* qpr = qpool + (size_t)bh * 50176 + (size_t)(qt * 64 + w * 16 + r) * 64;
  f32x4 qv[4];
  qv[0] = *(const f32x4*)&qpr[kg * 8];
  qv[1] = *(const f32x4*)&qpr[kg * 8 + 4];
  qv[2] = *(const f32x4*)&qpr[32 + kg * 8];
  qv[3] = *(const f32x4*)&qpr[32 + kg * 8 + 4];
  float s1 = 0.f, s2 = 0.f;
  #pragma unroll
  for (int i = 0; i < 4; i++)
    #pragma unroll
    for (int e = 0; e < 4; e++){ s1 += qv[i][e]; s2 += qv[i][e] * qv[i][e]; }
  s1 += __shfl_xor(s1, 16, 64); s1 += __shfl_xor(s1, 32, 64);
  s2 += __shfl_xor(s2, 16, 64); s2 += __shfl_xor(s2, 32, 64);
  const float mu = s1 * (1.f / 64.f);
  const float rs = rsqrtf(s2 * (1.f / 64.f) - mu * mu + 1e-5f);
  f32x4 lw[4], lb[4];
  lw[0] = *(const f32x4*)&nqw[kg * 8];      lw[1] = *(const f32x4*)&nqw[kg * 8 + 4];
  lw[2] = *(const f32x4*)&nqw[32 + kg * 8]; lw[3] = *(const f32x4*)&nqw[32 + kg * 8 + 4];
  lb[0] = *(const f32x4*)&nqb[kg * 8];      lb[1] = *(const f32x4*)&nqb[kg * 8 + 4];
  lb[2] = *(const f32x4*)&nqb[32 + kg * 8]; lb[3] = *(const f32x4*)&nqb[32 + kg * 8 + 4];
  short8 aq0, aq1;
  #pragma unroll
  for (int j = 0; j < 8; j++){
    float y0 = ((qv[j >> 2][j & 3] - mu) * rs * lw[j >> 2][j & 3] + lb[j >> 2][j & 3]) * 0.125f;
    float y1 = ((qv[2 + (j >> 2)][j & 3] - mu) * rs * lw[2 + (j >> 2)][j & 3] + lb[2 + (j >> 2)][j & 3]) * 0.125f;
    aq0[j] = (short)f2bf(y0);
    aq1[j] = (short)f2bf(y1);
  }

  __syncthreads();

  f32x4 s[13];
  #pragma unroll
  for (int nf = 0; nf < 13; nf++){
    int row = nf * 16 + r;
    short8 bk0 = *(const short8*)(K_lds + SWZ(row * 128 + kg * 16, row));
    short8 bk1 = *(const short8*)(K_lds + SWZ(row * 128 + 64 + kg * 16, row));
    f32x4 a = (f32x4){0.f, 0.f, 0.f, 0.f};
    a = __builtin_amdgcn_mfma_f32_16x16x32_bf16(aq0, bk0, a, 0, 0, 0);
    a = __builtin_amdgcn_mfma_f32_16x16x32_bf16(aq1, bk1, a, 0, 0, 0);
    s[nf] = a;
  }

  #pragma unroll
  for (int rg = 0; rg < 4; rg++) if (r >= 4) s[12][rg] = -1e30f;

  float inv[4];
  #pragma unroll
  for (int rg = 0; rg < 4; rg++){
    float m0 = s[0][rg];
    #pragma unroll
    for (int nf = 1; nf < 13; nf++) m0 = fmaxf(m0, s[nf][rg]);
    m0 = fmaxf(m0, __shfl_xor(m0, 1, 64));
    m0 = fmaxf(m0, __shfl_xor(m0, 2, 64));
    m0 = fmaxf(m0, __shfl_xor(m0, 4, 64));
    m0 = fmaxf(m0, __shfl_xor(m0, 8, 64));
    const int q = w * 16 + kg * 4 + rg;
    float sum = 0.f;
    #pragma unroll
    for (int nf = 0; nf < 13; nf++){
      float p = __expf(s[nf][rg] - m0);
      if (nf == 12 && r >= 4) p = 0.f;
      sum += p;
      *(unsigned short*)(P_lds + SWZ(q * 416 + (nf * 16 + r) * 2, q)) = f2bf(p);
    }
    sum += __shfl_xor(sum, 1, 64);
    sum += __shfl_xor(sum, 2, 64);
    sum += __shfl_xor(sum, 4, 64);
    sum += __shfl_xor(sum, 8, 64);
    inv[rg] = 1.f / sum;
  }

  f32x4 o[4];
  #pragma unroll
  for (int i = 0; i < 4; i++) o[i] = (f32x4){0.f, 0.f, 0.f, 0.f};
  const int qr = w * 16 + r;
  #pragma unroll
  for (int ks = 0; ks < 7; ks++){
    short8 ap = z8, bv0 = z8, bv1 = z8, bv2 = z8, bv3 = z8;
    if (ks < 6 || kg < 2){
      ap  = *(const short8*)(P_lds + SWZ(qr * 416 + ks * 64 + kg * 16, qr));
      bv0 = *(const short8*)(V_lds + SWZ((0 * 16 + r) * 416 + ks * 64 + kg * 16, (0 * 16 + r)));
      bv1 = *(const short8*)(V_lds + SWZ((1 * 16 + r) * 416 + ks * 64 + kg * 16, (1 * 16 + r)));
      bv2 = *(const short8*)(V_lds + SWZ((2 * 16 + r) * 416 + ks * 64 + kg * 16, (2 * 16 + r)));
      bv3 = *(const short8*)(V_lds + SWZ((3 * 16 + r) * 416 + ks * 64 + kg * 16, (3 * 16 + r)));
    }
    o[0] = __builtin_amdgcn_mfma_f32_16x16x32_bf16(ap, bv0, o[0], 0, 0, 0);
    o[1] = __builtin_amdgcn_mfma_f32_16x16x32_bf16(ap, bv1, o[1], 0, 0, 0);
    o[2] = __builtin_amdgcn_mfma_f32_16x16x32_bf16(ap, bv2, o[2], 0, 0, 0);
    o[3] = __builtin_amdgcn_mfma_f32_16x16x32_bf16(ap, bv3, o[3], 0, 0, 0);
  }

  #pragma unroll
  for (int rg = 0; rg < 4; rg++){
    int qg = qt * 64 + w * 16 + kg * 4 + rg;
    if (qg < 784){
      unsigned short* orow = out + ((size_t)b * 784 + qg) * 768 + h * 64;
      float sc = inv[rg];
      orow[ 0 + r] = f2bf(o[0][rg] * sc);
      orow[16 + r] = f2bf(o[1][rg] * sc);
      orow[32 + r] = f2bf(o[2][rg] * sc);
      orow[48 + r] = f2bf(o[3][rg] * sc);
    }
  }
}

// ---------------------------------------------------------------- launch
extern "C" void kernel_launch(void* const* d_in, const int* in_sizes, int n_in,
                              void* d_out, int out_size, void* d_ws, size_t ws_size,
                              hipStream_t stream)
{
  (void)in_sizes; (void)n_in; (void)out_size; (void)ws_size;
  const float* x      = (const float*)d_in[0];
  const float* norm_w = (const float*)d_in[3];
  const float* norm_b = (const float*)d_in[4];
  const float* qkv_w  = (const float*)d_in[5];
  const float* qkv_b  = (const float*)d_in[6];
  const float* pq_w   = (const float*)d_in[7];
  const float* pk_w   = (const float*)d_in[8];
  const float* pv_w   = (const float*)d_in[9];
  const float* nq_w   = (const float*)d_in[10];
  const float* nq_b   = (const float*)d_in[11];
  const float* nk_w   = (const float*)d_in[12];
  const float* nk_b   = (const float*)d_in[13];
  const float* nv_w   = (const float*)d_in[14];
  const float* nv_b   = (const float*)d_in[15];
  const float* proj_w = (const float*)d_in[16];
  const float* proj_b = (const float*)d_in[17];
  float* outp = (float*)d_out;

  char* ws = (char*)d_ws;
  size_t o = 0;
  unsigned short* wqkv16  = (unsigned short*)(ws + o); o += 3538944;    // 2304x768 bf16
  unsigned short* wproj16 = (unsigned short*)(ws + o); o += 1179648;    // 768x768 bf16
  unsigned short* wv16    = (unsigned short*)(ws + o); o += 131072;     // 64x1024 bf16
  char* xn_region         = (ws + o);                  o += 77070336;   // xn; later Kbt/Vtb
  float*  qpool           = (float*)(ws + o);          o += 38535168;   // 192x50176 f32
  float*  kpool           = (float*)(ws + o);          o += 9633792;    // 192x12544 f32
  float*  vpool           = (float*)(ws + o);          o += 9633792;
  unsigned short* attno   = (unsigned short*)(ws + o); o += 19267584;   // 12544x768 bf16

  unsigned short* xn  = (unsigned short*)xn_region;
  unsigned short* Kbt = (unsigned short*)(xn_region + 19275776);
  unsigned short* Vtb = (unsigned short*)(xn_region + 19275776 + 5111808);

  tobf16_kernel<<<(1769472 + 255) / 256, 256, 0, stream>>>(qkv_w, wqkv16, 1769472);
  tobf16_kernel<<<(589824 + 255) / 256, 256, 0, stream>>>(proj_w, wproj16, 589824);
  conv_wv_kernel<<<256, 256, 0, stream>>>(pv_w, wv16);

  ln768_kernel<<<12544, 256, 0, stream>>>(x, norm_w, norm_b, xn);

  gemm_qkv<<<196 * 9, 512, 0, stream>>>(xn, wqkv16, qkv_b, pq_w, pk_w, wv16,
                                        qpool, kpool, vpool);

  ln64k_kernel<<<37632 / 4, 256, 0, stream>>>(kpool, nk_w, nk_b, Kbt);
  vt_prep_kernel<<<192, 256, 0, stream>>>(vpool, nv_w, nv_b, Vtb);

  attn2_kernel<<<192 * 13, 256, 0, stream>>>(qpool, nq_w, nq_b, Kbt, Vtb, attno);

  gemm_bt<0><<<98 * 6, 256, 0, stream>>>(attno, wproj16, proj_b, outp, 12544, 768, 768);
}